// Round 1
// baseline (2147.532 us; speedup 1.0000x reference)
//
#include <hip/hip_runtime.h>
#include <hip/hip_bf16.h>

#define T_TOK 2048
#define DIM   2048
#define NE    8
#define NH    5632

typedef __attribute__((ext_vector_type(4))) float f32x4;
typedef __attribute__((ext_vector_type(8))) short short8;
typedef __attribute__((ext_vector_type(4))) unsigned int u32x4;
typedef __attribute__((ext_vector_type(4))) float float4v;

__device__ inline unsigned short f2bf(float f) {
    unsigned u = __builtin_bit_cast(unsigned, f);
    u += 0x7fffu + ((u >> 16) & 1u);       // round-to-nearest-even
    return (unsigned short)(u >> 16);
}

// ---------------- kernel 0: x (fp32) -> xb (bf16) ----------------
__global__ void k_cvt_x(const float* __restrict__ x, unsigned short* __restrict__ xb) {
    int i = blockIdx.x * blockDim.x + threadIdx.x;   // T*D/8 threads
    const float4v* xv = (const float4v*)x;
    float4v a = xv[2 * i], b = xv[2 * i + 1];
    short8 o;
    o[0] = (short)f2bf(a[0]); o[1] = (short)f2bf(a[1]);
    o[2] = (short)f2bf(a[2]); o[3] = (short)f2bf(a[3]);
    o[4] = (short)f2bf(b[0]); o[5] = (short)f2bf(b[1]);
    o[6] = (short)f2bf(b[2]); o[7] = (short)f2bf(b[3]);
    ((short8*)xb)[i] = o;
}

// ---------------- kernel 1: gating (fp32, one wave per token) ----------------
__global__ void k_gate(const float* __restrict__ x, const float* __restrict__ gw,
                       int* __restrict__ rt_e, float* __restrict__ rt_w) {
    int wid = threadIdx.x >> 6, lane = threadIdx.x & 63;
    int t = blockIdx.x * 4 + wid;
    if (t >= T_TOK) return;
    float acc[NE];
#pragma unroll
    for (int e = 0; e < NE; e++) acc[e] = 0.f;
    const float* xr = x + (size_t)t * DIM;
    for (int d = lane; d < DIM; d += 64) {
        float xv = xr[d];
#pragma unroll
        for (int e = 0; e < NE; e++) acc[e] += xv * gw[e * DIM + d];
    }
#pragma unroll
    for (int e = 0; e < NE; e++) {
        float v = acc[e];
#pragma unroll
        for (int off = 32; off; off >>= 1) v += __shfl_xor(v, off);
        acc[e] = v;
    }
    if (lane == 0) {
        int i0 = 0; float s0 = acc[0];
#pragma unroll
        for (int e = 1; e < NE; e++) if (acc[e] > s0) { s0 = acc[e]; i0 = e; }
        int i1 = -1; float s1 = -1e30f;
#pragma unroll
        for (int e = 0; e < NE; e++) if (e != i0 && acc[e] > s1) { s1 = acc[e]; i1 = e; }
        float w0 = 1.f / (1.f + expf(s1 - s0));   // softmax over {s0,s1}, s0 >= s1
        rt_e[2 * t] = i0; rt_e[2 * t + 1] = i1;
        rt_w[2 * t] = w0; rt_w[2 * t + 1] = 1.f - w0;
    }
}

// ---------------- kernel 2: count per expert ----------------
__global__ void k_count(const int* __restrict__ rt_e, int* __restrict__ cnt) {
    int t = blockIdx.x * blockDim.x + threadIdx.x;
    if (t >= T_TOK) return;
    atomicAdd(&cnt[rt_e[2 * t]], 1);
    atomicAdd(&cnt[rt_e[2 * t + 1]], 1);
}

// ---------------- kernel 3: exclusive prefix over 8 counts ----------------
__global__ void k_base(const int* __restrict__ cnt, int* __restrict__ base) {
    if (threadIdx.x == 0) {
        int s = 0;
        for (int e = 0; e < NE; e++) { base[e] = s; s += cnt[e]; }
    }
}

// ---------------- kernel 4: assign slots ----------------
__global__ void k_assign(const int* __restrict__ rt_e, const float* __restrict__ rt_w,
                         const int* __restrict__ base, int* __restrict__ run,
                         int* __restrict__ tok, float* __restrict__ tw) {
    int t = blockIdx.x * blockDim.x + threadIdx.x;
    if (t >= T_TOK) return;
#pragma unroll
    for (int k = 0; k < 2; k++) {
        int e = rt_e[2 * t + k];
        int p = atomicAdd(&run[e], 1);
        int g = base[e] + p;
        tok[g] = t;
        tw[g] = rt_w[2 * t + k];
    }
}

// ---------------- kernel 5: GEMM1 fused  h = silu(x@w1^T) * (x@w3^T) ----------------
// tile BM=128 slots x BN=64 h-cols, BK=64, 4 waves (2x2), wave tile 64x32 per matrix
__launch_bounds__(256)
__global__ void k_ffn1(const unsigned short* __restrict__ xb,
                       const float* __restrict__ w1, const float* __restrict__ w3,
                       const int* __restrict__ cnt, const int* __restrict__ base,
                       const int* __restrict__ tok, unsigned short* __restrict__ hbuf) {
    int e  = blockIdx.x >> 4;
    int mt = blockIdx.x & 15;
    int c  = cnt[e];
    int m0 = mt * 128;
    if (m0 >= c) return;
    int gb = base[e];
    int n0 = blockIdx.y * 64;

    __shared__ unsigned short As[128 * 64];
    __shared__ unsigned short B1s[64 * 64];
    __shared__ unsigned short B3s[64 * 64];
    __shared__ int toks[128];

    int tid = threadIdx.x;
    if (tid < 128) {
        int s = m0 + tid;
        toks[tid] = (s < c) ? tok[gb + s] : tok[gb];
    }

    int lane = tid & 63, wid = tid >> 6;
    int wm = wid >> 1, wn = wid & 1;

    f32x4 acc1[4][2], acc3[4][2];
#pragma unroll
    for (int i = 0; i < 4; i++)
#pragma unroll
        for (int j = 0; j < 2; j++) { acc1[i][j] = (f32x4)0.f; acc3[i][j] = (f32x4)0.f; }

    const float* W1 = w1 + (size_t)e * NH * DIM + (size_t)n0 * DIM;
    const float* W3 = w3 + (size_t)e * NH * DIM + (size_t)n0 * DIM;

    for (int kt = 0; kt < DIM / 64; ++kt) {
        int k0 = kt * 64;
        __syncthreads();
        // stage A: 128 rows x 64 bf16 (8 chunks of 16B per row), gathered by token id
#pragma unroll
        for (int i = 0; i < 4; i++) {
            int f = i * 256 + tid;
            int row = f >> 3, ch = f & 7;
            u32x4 v = *(const u32x4*)(xb + (size_t)toks[row] * DIM + k0 + ch * 8);
            *(u32x4*)(As + row * 64 + ((ch ^ (row & 7)) << 3)) = v;
        }
        // stage B1/B3: 64 rows x 64 fp32 -> bf16 (8 chunks of 8 per row)
#pragma unroll
        for (int i = 0; i < 2; i++) {
            int f = i * 256 + tid;
            int row = f >> 3, ch = f & 7;
            {
                const float* src = W1 + (size_t)row * DIM + k0 + ch * 8;
                float4v a = *(const float4v*)src, b = *(const float4v*)(src + 4);
                short8 o;
                o[0]=(short)f2bf(a[0]); o[1]=(short)f2bf(a[1]); o[2]=(short)f2bf(a[2]); o[3]=(short)f2bf(a[3]);
                o[4]=(short)f2bf(b[0]); o[5]=(short)f2bf(b[1]); o[6]=(short)f2bf(b[2]); o[7]=(short)f2bf(b[3]);
                *(short8*)(B1s + row * 64 + ((ch ^ (row & 7)) << 3)) = o;
            }
            {
                const float* src = W3 + (size_t)row * DIM + k0 + ch * 8;
                float4v a = *(const float4v*)src, b = *(const float4v*)(src + 4);
                short8 o;
                o[0]=(short)f2bf(a[0]); o[1]=(short)f2bf(a[1]); o[2]=(short)f2bf(a[2]); o[3]=(short)f2bf(a[3]);
                o[4]=(short)f2bf(b[0]); o[5]=(short)f2bf(b[1]); o[6]=(short)f2bf(b[2]); o[7]=(short)f2bf(b[3]);
                *(short8*)(B3s + row * 64 + ((ch ^ (row & 7)) << 3)) = o;
            }
        }
        __syncthreads();
#pragma unroll
        for (int kk = 0; kk < 2; kk++) {
            int kch = kk * 4 + (lane >> 4);
            short8 af[4], b1f[2], b3f[2];
#pragma unroll
            for (int mf = 0; mf < 4; mf++) {
                int r = wm * 64 + mf * 16 + (lane & 15);
                af[mf] = *(const short8*)(As + r * 64 + ((kch ^ (r & 7)) << 3));
            }
#pragma unroll
            for (int nf = 0; nf < 2; nf++) {
                int r = wn * 32 + nf * 16 + (lane & 15);
                b1f[nf] = *(const short8*)(B1s + r * 64 + ((kch ^ (r & 7)) << 3));
                b3f[nf] = *(const short8*)(B3s + r * 64 + ((kch ^ (r & 7)) << 3));
            }
#pragma unroll
            for (int mf = 0; mf < 4; mf++)
#pragma unroll
                for (int nf = 0; nf < 2; nf++) {
                    acc1[mf][nf] = __builtin_amdgcn_mfma_f32_16x16x32_bf16(af[mf], b1f[nf], acc1[mf][nf], 0, 0, 0);
                    acc3[mf][nf] = __builtin_amdgcn_mfma_f32_16x16x32_bf16(af[mf], b3f[nf], acc3[mf][nf], 0, 0, 0);
                }
        }
    }
    // epilogue: h = silu(acc1) * acc3, store bf16
#pragma unroll
    for (int mf = 0; mf < 4; mf++)
#pragma unroll
        for (int nf = 0; nf < 2; nf++)
#pragma unroll
            for (int r = 0; r < 4; r++) {
                int row = wm * 64 + mf * 16 + ((lane >> 4) << 2) + r;
                int col = wn * 32 + nf * 16 + (lane & 15);
                if (m0 + row < c) {
                    float a = acc1[mf][nf][r];
                    float g = a / (1.f + expf(-a));
                    float v = g * acc3[mf][nf][r];
                    hbuf[(size_t)(gb + m0 + row) * NH + n0 + col] = f2bf(v);
                }
            }
}

// ---------------- kernel 6: GEMM2  y[t] += gate_w * (h @ w2^T) ----------------
// tile BM=128 slots x BN=128 d-cols, BK=64, 4 waves (2x2), wave tile 64x64
__launch_bounds__(256)
__global__ void k_ffn2(const unsigned short* __restrict__ hbuf,
                       const float* __restrict__ w2,
                       const int* __restrict__ cnt, const int* __restrict__ base,
                       const int* __restrict__ tok, const float* __restrict__ tw,
                       float* __restrict__ y) {
    int e  = blockIdx.x >> 4;
    int mt = blockIdx.x & 15;
    int c  = cnt[e];
    int m0 = mt * 128;
    if (m0 >= c) return;
    int gb = base[e];
    int n0 = blockIdx.y * 128;

    __shared__ unsigned short As[128 * 64];
    __shared__ unsigned short Bs[128 * 64];
    __shared__ int   toks[128];
    __shared__ float gws[128];

    int tid = threadIdx.x;
    if (tid < 128) {
        int s = m0 + tid;
        toks[tid] = (s < c) ? tok[gb + s] : 0;
        gws[tid]  = (s < c) ? tw[gb + s] : 0.f;
    }

    int lane = tid & 63, wid = tid >> 6;
    int wm = wid >> 1, wn = wid & 1;

    f32x4 acc[4][4];
#pragma unroll
    for (int i = 0; i < 4; i++)
#pragma unroll
        for (int j = 0; j < 4; j++) acc[i][j] = (f32x4)0.f;

    const float* W2 = w2 + (size_t)e * DIM * NH + (size_t)n0 * NH;

    for (int kt = 0; kt < NH / 64; ++kt) {
        int k0 = kt * 64;
        __syncthreads();
        // stage A: 128 slot-rows x 64 bf16 from hbuf (contiguous rows, clamped)
#pragma unroll
        for (int i = 0; i < 4; i++) {
            int f = i * 256 + tid;
            int row = f >> 3, ch = f & 7;
            int rr = m0 + row; rr = (rr < c) ? rr : (c - 1);
            u32x4 v = *(const u32x4*)(hbuf + (size_t)(gb + rr) * NH + k0 + ch * 8);
            *(u32x4*)(As + row * 64 + ((ch ^ (row & 7)) << 3)) = v;
        }
        // stage B: 128 d-rows x 64 fp32 -> bf16
#pragma unroll
        for (int i = 0; i < 4; i++) {
            int f = i * 256 + tid;
            int row = f >> 3, ch = f & 7;
            const float* src = W2 + (size_t)row * NH + k0 + ch * 8;
            float4v a = *(const float4v*)src, b = *(const float4v*)(src + 4);
            short8 o;
            o[0]=(short)f2bf(a[0]); o[1]=(short)f2bf(a[1]); o[2]=(short)f2bf(a[2]); o[3]=(short)f2bf(a[3]);
            o[4]=(short)f2bf(b[0]); o[5]=(short)f2bf(b[1]); o[6]=(short)f2bf(b[2]); o[7]=(short)f2bf(b[3]);
            *(short8*)(Bs + row * 64 + ((ch ^ (row & 7)) << 3)) = o;
        }
        __syncthreads();
#pragma unroll
        for (int kk = 0; kk < 2; kk++) {
            int kch = kk * 4 + (lane >> 4);
            short8 af[4], bf[4];
#pragma unroll
            for (int mf = 0; mf < 4; mf++) {
                int r = wm * 64 + mf * 16 + (lane & 15);
                af[mf] = *(const short8*)(As + r * 64 + ((kch ^ (r & 7)) << 3));
            }
#pragma unroll
            for (int nf = 0; nf < 4; nf++) {
                int r = wn * 64 + nf * 16 + (lane & 15);
                bf[nf] = *(const short8*)(Bs + r * 64 + ((kch ^ (r & 7)) << 3));
            }
#pragma unroll
            for (int mf = 0; mf < 4; mf++)
#pragma unroll
                for (int nf = 0; nf < 4; nf++)
                    acc[mf][nf] = __builtin_amdgcn_mfma_f32_16x16x32_bf16(af[mf], bf[nf], acc[mf][nf], 0, 0, 0);
        }
    }
    // epilogue: scale by gate weight, atomic-add into y (exactly 2 adds/elem -> deterministic)
#pragma unroll
    for (int mf = 0; mf < 4; mf++)
#pragma unroll
        for (int nf = 0; nf < 4; nf++)
#pragma unroll
            for (int r = 0; r < 4; r++) {
                int row = wm * 64 + mf * 16 + ((lane >> 4) << 2) + r;
                int col = wn * 64 + nf * 16 + (lane & 15);
                if (m0 + row < c) {
                    float v = gws[row] * acc[mf][nf][r];
                    atomicAdd(&y[(size_t)toks[row] * DIM + n0 + col], v);
                }
            }
}

// ---------------- launch ----------------
extern "C" void kernel_launch(void* const* d_in, const int* in_sizes, int n_in,
                              void* d_out, int out_size, void* d_ws, size_t ws_size,
                              hipStream_t stream) {
    const float* x  = (const float*)d_in[0];
    const float* gw = (const float*)d_in[1];
    const float* w1 = (const float*)d_in[2];
    const float* w2 = (const float*)d_in[3];
    const float* w3 = (const float*)d_in[4];
    float* y = (float*)d_out;

    char* ws = (char*)d_ws;
    int*   cnt  = (int*)(ws + 0);              // 8 ints
    int*   run  = (int*)(ws + 64);             // 8 ints
    int*   basep= (int*)(ws + 128);            // 8 ints
    int*   tok  = (int*)(ws + 256);            // 4096 ints
    float* tw   = (float*)(ws + 16640);        // 4096 floats
    int*   rt_e = (int*)(ws + 33024);          // 4096 ints
    float* rt_w = (float*)(ws + 49408);        // 4096 floats
    unsigned short* xb   = (unsigned short*)(ws + 65792);             // 8 MB
    unsigned short* hbuf = (unsigned short*)(ws + 65792 + 8388608);   // 46 MB

    hipMemsetAsync(ws, 0, 256, stream);
    hipMemsetAsync(d_out, 0, (size_t)out_size * sizeof(float), stream);

    k_cvt_x<<<(T_TOK * DIM / 8) / 256, 256, 0, stream>>>(x, xb);
    k_gate<<<T_TOK / 4, 256, 0, stream>>>(x, gw, rt_e, rt_w);
    k_count<<<T_TOK / 256, 256, 0, stream>>>(rt_e, cnt);
    k_base<<<1, 64, 0, stream>>>(cnt, basep);
    k_assign<<<T_TOK / 256, 256, 0, stream>>>(rt_e, rt_w, basep, run, tok, tw);
    k_ffn1<<<dim3(NE * 16, NH / 64), 256, 0, stream>>>(xb, w1, w3, cnt, basep, tok, hbuf);
    k_ffn2<<<dim3(NE * 16, DIM / 128), 256, 0, stream>>>(hbuf, w2, cnt, basep, tok, tw, y);
}

// Round 2
// 1473.768 us; speedup vs baseline: 1.4572x; 1.4572x over previous
//
#include <hip/hip_runtime.h>
#include <hip/hip_bf16.h>

#define T_TOK 2048
#define DIM   2048
#define NE    8
#define NH    5632

typedef __attribute__((ext_vector_type(4))) float f32x4;
typedef __attribute__((ext_vector_type(8))) short short8;
typedef __attribute__((ext_vector_type(4))) unsigned int u32x4;
typedef __attribute__((ext_vector_type(4))) float float4v;

__device__ inline unsigned short f2bf(float f) {
    unsigned u = __builtin_bit_cast(unsigned, f);
    u += 0x7fffu + ((u >> 16) & 1u);       // round-to-nearest-even
    return (unsigned short)(u >> 16);
}

__device__ __forceinline__ void glds16(const void* g, void* l) {
    __builtin_amdgcn_global_load_lds((const __attribute__((address_space(1))) void*)g,
                                     (__attribute__((address_space(3))) void*)l, 16, 0, 0);
}

// ---------------- kernel 0: fp32 -> bf16 bulk convert ----------------
__global__ void k_cvt(const float* __restrict__ src, unsigned short* __restrict__ dst, int n8) {
    int i = blockIdx.x * blockDim.x + threadIdx.x;
    if (i >= n8) return;
    const float4v* xv = (const float4v*)src;
    float4v a = xv[2 * i], b = xv[2 * i + 1];
    short8 o;
    o[0] = (short)f2bf(a[0]); o[1] = (short)f2bf(a[1]);
    o[2] = (short)f2bf(a[2]); o[3] = (short)f2bf(a[3]);
    o[4] = (short)f2bf(b[0]); o[5] = (short)f2bf(b[1]);
    o[6] = (short)f2bf(b[2]); o[7] = (short)f2bf(b[3]);
    ((short8*)dst)[i] = o;
}

// ---------------- kernel 1: gating (fp32, one wave per token) ----------------
__global__ void k_gate(const float* __restrict__ x, const float* __restrict__ gw,
                       int* __restrict__ rt_e, float* __restrict__ rt_w) {
    int wid = threadIdx.x >> 6, lane = threadIdx.x & 63;
    int t = blockIdx.x * 4 + wid;
    if (t >= T_TOK) return;
    float acc[NE];
#pragma unroll
    for (int e = 0; e < NE; e++) acc[e] = 0.f;
    const float* xr = x + (size_t)t * DIM;
    for (int d = lane; d < DIM; d += 64) {
        float xv = xr[d];
#pragma unroll
        for (int e = 0; e < NE; e++) acc[e] += xv * gw[e * DIM + d];
    }
#pragma unroll
    for (int e = 0; e < NE; e++) {
        float v = acc[e];
#pragma unroll
        for (int off = 32; off; off >>= 1) v += __shfl_xor(v, off);
        acc[e] = v;
    }
    if (lane == 0) {
        int i0 = 0; float s0 = acc[0];
#pragma unroll
        for (int e = 1; e < NE; e++) if (acc[e] > s0) { s0 = acc[e]; i0 = e; }
        int i1 = -1; float s1 = -1e30f;
#pragma unroll
        for (int e = 0; e < NE; e++) if (e != i0 && acc[e] > s1) { s1 = acc[e]; i1 = e; }
        float w0 = 1.f / (1.f + expf(s1 - s0));   // softmax over {s0,s1}, s0 >= s1
        rt_e[2 * t] = i0; rt_e[2 * t + 1] = i1;
        rt_w[2 * t] = w0; rt_w[2 * t + 1] = 1.f - w0;
    }
}

// ---------------- kernel 2: count per expert ----------------
__global__ void k_count(const int* __restrict__ rt_e, int* __restrict__ cnt) {
    int t = blockIdx.x * blockDim.x + threadIdx.x;
    if (t >= T_TOK) return;
    atomicAdd(&cnt[rt_e[2 * t]], 1);
    atomicAdd(&cnt[rt_e[2 * t + 1]], 1);
}

// ---------------- kernel 3: exclusive prefix over 8 counts ----------------
__global__ void k_base(const int* __restrict__ cnt, int* __restrict__ base) {
    if (threadIdx.x == 0) {
        int s = 0;
        for (int e = 0; e < NE; e++) { base[e] = s; s += cnt[e]; }
    }
}

// ---------------- kernel 4: assign slots ----------------
__global__ void k_assign(const int* __restrict__ rt_e, const float* __restrict__ rt_w,
                         const int* __restrict__ base, int* __restrict__ run,
                         int* __restrict__ tok, float* __restrict__ tw) {
    int t = blockIdx.x * blockDim.x + threadIdx.x;
    if (t >= T_TOK) return;
#pragma unroll
    for (int k = 0; k < 2; k++) {
        int e = rt_e[2 * t + k];
        int p = atomicAdd(&run[e], 1);
        int g = base[e] + p;
        tok[g] = t;
        tw[g] = rt_w[2 * t + k];
    }
}

// =====================================================================
// FAST PATH: bf16 weights, global_load_lds staging, m97-style K-loop
// =====================================================================

// GEMM1: h = silu(x@w1^T) * (x@w3^T).  Tile 128M x 64N, BK=64, 4 waves (2x2).
// LDS layouts: A[kc=8][row=128][8 bf16] kc-stride 2064B; B[kc=8][row=64][8] kc-stride 1040B.
__launch_bounds__(256)
__global__ void k_ffn1(const unsigned short* __restrict__ xb,
                       const unsigned short* __restrict__ w1b, const unsigned short* __restrict__ w3b,
                       const int* __restrict__ cnt, const int* __restrict__ base,
                       const int* __restrict__ tok, unsigned short* __restrict__ hbuf, int nwg) {
    int bid = blockIdx.x;
    int swz = (bid & 7) * (nwg >> 3) + (bid >> 3);   // XCD-chunked, bijective (nwg%8==0)
    int mt = swz & 15;
    int r2 = swz >> 4;
    int n  = r2 % 88;
    int e  = r2 / 88;
    int c  = cnt[e];
    int m0 = mt * 128;
    if (m0 >= c) return;
    int gb = base[e];
    int n0 = n * 64;

    __shared__ unsigned short As[8 * 1032];     // 16512 B
    __shared__ unsigned short B1s[8 * 520];     // 8320 B
    __shared__ unsigned short B3s[8 * 520];     // 8320 B
    __shared__ int toks[128];

    int tid = threadIdx.x;
    if (tid < 128) {
        int s = m0 + tid;
        toks[tid] = (s < c) ? tok[gb + s] : tok[gb];
    }
    __syncthreads();

    int lane = tid & 63, w = tid >> 6;
    int wm = w >> 1, wn = w & 1;
    int half = w & 1, wh = w >> 1;

    // per-thread staging sources (fixed row per thread; kc varies per issue)
    int ra = half * 64 + lane;
    const unsigned short* aSrc  = xb  + (size_t)toks[ra] * DIM;
    const unsigned short* b1Src = w1b + (size_t)e * NH * DIM + (size_t)(n0 + lane) * DIM;
    const unsigned short* b3Src = w3b + (size_t)e * NH * DIM + (size_t)(n0 + lane) * DIM;

    f32x4 acc1[4][2], acc3[4][2];
#pragma unroll
    for (int i = 0; i < 4; i++)
#pragma unroll
        for (int j = 0; j < 2; j++) { acc1[i][j] = (f32x4)0.f; acc3[i][j] = (f32x4)0.f; }

    for (int kt = 0; kt < DIM / 64; ++kt) {
        int k0 = kt * 64;
        __syncthreads();      // prior compute done with LDS
        // A: 16 chunks of (kc,half); this thread serves kc = i*2+wh, its fixed half
#pragma unroll
        for (int i = 0; i < 4; i++) {
            int kc = i * 2 + wh;
            glds16(aSrc + k0 + kc * 8, As + kc * 1032 + half * 512);
        }
        // B1/B3: 8 chunks each; this thread serves kc = i*4+w
#pragma unroll
        for (int i = 0; i < 2; i++) {
            int kc = i * 4 + w;
            glds16(b1Src + k0 + kc * 8, B1s + kc * 520);
            glds16(b3Src + k0 + kc * 8, B3s + kc * 520);
        }
        asm volatile("s_waitcnt vmcnt(0)" ::: "memory");
        __syncthreads();
#pragma unroll
        for (int kh = 0; kh < 2; kh++) {
            int kc = kh * 4 + (lane >> 4);
            short8 a[4], b1[2], b3[2];
#pragma unroll
            for (int mf = 0; mf < 4; mf++) {
                int r = wm * 64 + mf * 16 + (lane & 15);
                a[mf] = *(const short8*)(As + kc * 1032 + r * 8);
            }
#pragma unroll
            for (int nf = 0; nf < 2; nf++) {
                int rb = wn * 32 + nf * 16 + (lane & 15);
                b1[nf] = *(const short8*)(B1s + kc * 520 + rb * 8);
                b3[nf] = *(const short8*)(B3s + kc * 520 + rb * 8);
            }
#pragma unroll
            for (int mf = 0; mf < 4; mf++)
#pragma unroll
                for (int nf = 0; nf < 2; nf++) {
                    acc1[mf][nf] = __builtin_amdgcn_mfma_f32_16x16x32_bf16(a[mf], b1[nf], acc1[mf][nf], 0, 0, 0);
                    acc3[mf][nf] = __builtin_amdgcn_mfma_f32_16x16x32_bf16(a[mf], b3[nf], acc3[mf][nf], 0, 0, 0);
                }
        }
    }
#pragma unroll
    for (int mf = 0; mf < 4; mf++)
#pragma unroll
        for (int nf = 0; nf < 2; nf++)
#pragma unroll
            for (int r = 0; r < 4; r++) {
                int row = wm * 64 + mf * 16 + ((lane >> 4) << 2) + r;
                int col = wn * 32 + nf * 16 + (lane & 15);
                if (m0 + row < c) {
                    float a = acc1[mf][nf][r];
                    float g = a / (1.f + expf(-a));
                    float v = g * acc3[mf][nf][r];
                    hbuf[(size_t)(gb + m0 + row) * NH + n0 + col] = f2bf(v);
                }
            }
}

// GEMM2: y[t] += gate_w * (h @ w2^T). Tile 128M x 128N, BK=64, 4 waves (2x2).
// LDS: A[8][128][8] stride 2064B; B[8][128][8] stride 2064B.
__launch_bounds__(256)
__global__ void k_ffn2(const unsigned short* __restrict__ hbuf,
                       const unsigned short* __restrict__ w2b,
                       const int* __restrict__ cnt, const int* __restrict__ base,
                       const int* __restrict__ tok, const float* __restrict__ tw,
                       float* __restrict__ y, int nwg) {
    int bid = blockIdx.x;
    int swz = (bid & 7) * (nwg >> 3) + (bid >> 3);
    int mt = swz & 15;
    int r2 = swz >> 4;
    int n  = r2 & 15;
    int e  = r2 >> 4;
    int c  = cnt[e];
    int m0 = mt * 128;
    if (m0 >= c) return;
    int gb = base[e];
    int n0 = n * 128;

    __shared__ unsigned short As[8 * 1032];
    __shared__ unsigned short Bs[8 * 1032];
    __shared__ int   toks[128];
    __shared__ float gws[128];

    int tid = threadIdx.x;
    if (tid < 128) {
        int s = m0 + tid;
        toks[tid] = (s < c) ? tok[gb + s] : 0;
        gws[tid]  = (s < c) ? tw[gb + s] : 0.f;
    }
    __syncthreads();

    int lane = tid & 63, w = tid >> 6;
    int wm = w >> 1, wn = w & 1;
    int half = w & 1, wh = w >> 1;

    int rowA = half * 64 + lane;
    int slot = m0 + rowA; if (slot >= c) slot = c - 1;
    const unsigned short* aSrc = hbuf + (size_t)(gb + slot) * NH;
    const unsigned short* bSrc = w2b + (size_t)e * DIM * NH + (size_t)(n0 + rowA) * NH;

    f32x4 acc[4][4];
#pragma unroll
    for (int i = 0; i < 4; i++)
#pragma unroll
        for (int j = 0; j < 4; j++) acc[i][j] = (f32x4)0.f;

    for (int kt = 0; kt < NH / 64; ++kt) {
        int k0 = kt * 64;
        __syncthreads();
#pragma unroll
        for (int i = 0; i < 4; i++) {
            int kc = i * 2 + wh;
            glds16(aSrc + k0 + kc * 8, As + kc * 1032 + half * 512);
            glds16(bSrc + k0 + kc * 8, Bs + kc * 1032 + half * 512);
        }
        asm volatile("s_waitcnt vmcnt(0)" ::: "memory");
        __syncthreads();
#pragma unroll
        for (int kh = 0; kh < 2; kh++) {
            int kc = kh * 4 + (lane >> 4);
            short8 a[4], b[4];
#pragma unroll
            for (int mf = 0; mf < 4; mf++) {
                int r = wm * 64 + mf * 16 + (lane & 15);
                a[mf] = *(const short8*)(As + kc * 1032 + r * 8);
            }
#pragma unroll
            for (int nf = 0; nf < 4; nf++) {
                int rb = wn * 64 + nf * 16 + (lane & 15);
                b[nf] = *(const short8*)(Bs + kc * 1032 + rb * 8);
            }
#pragma unroll
            for (int mf = 0; mf < 4; mf++)
#pragma unroll
                for (int nf = 0; nf < 4; nf++)
                    acc[mf][nf] = __builtin_amdgcn_mfma_f32_16x16x32_bf16(a[mf], b[nf], acc[mf][nf], 0, 0, 0);
        }
    }
#pragma unroll
    for (int mf = 0; mf < 4; mf++)
#pragma unroll
        for (int nf = 0; nf < 4; nf++)
#pragma unroll
            for (int r = 0; r < 4; r++) {
                int row = wm * 64 + mf * 16 + ((lane >> 4) << 2) + r;
                int col = wn * 64 + nf * 16 + (lane & 15);
                if (m0 + row < c) {
                    float v = gws[row] * acc[mf][nf][r];
                    atomicAdd(&y[(size_t)toks[row] * DIM + n0 + col], v);
                }
            }
}

// =====================================================================
// FALLBACK PATH (round-0 kernels, on-the-fly fp32->bf16 conversion)
// =====================================================================
__launch_bounds__(256)
__global__ void k_ffn1_fb(const unsigned short* __restrict__ xb,
                          const float* __restrict__ w1, const float* __restrict__ w3,
                          const int* __restrict__ cnt, const int* __restrict__ base,
                          const int* __restrict__ tok, unsigned short* __restrict__ hbuf) {
    int e  = blockIdx.x >> 4;
    int mt = blockIdx.x & 15;
    int c  = cnt[e];
    int m0 = mt * 128;
    if (m0 >= c) return;
    int gb = base[e];
    int n0 = blockIdx.y * 64;

    __shared__ unsigned short As[128 * 64];
    __shared__ unsigned short B1s[64 * 64];
    __shared__ unsigned short B3s[64 * 64];
    __shared__ int toks[128];

    int tid = threadIdx.x;
    if (tid < 128) {
        int s = m0 + tid;
        toks[tid] = (s < c) ? tok[gb + s] : tok[gb];
    }
    int lane = tid & 63, wid = tid >> 6;
    int wm = wid >> 1, wn = wid & 1;

    f32x4 acc1[4][2], acc3[4][2];
#pragma unroll
    for (int i = 0; i < 4; i++)
#pragma unroll
        for (int j = 0; j < 2; j++) { acc1[i][j] = (f32x4)0.f; acc3[i][j] = (f32x4)0.f; }

    const float* W1 = w1 + (size_t)e * NH * DIM + (size_t)n0 * DIM;
    const float* W3 = w3 + (size_t)e * NH * DIM + (size_t)n0 * DIM;

    for (int kt = 0; kt < DIM / 64; ++kt) {
        int k0 = kt * 64;
        __syncthreads();
#pragma unroll
        for (int i = 0; i < 4; i++) {
            int f = i * 256 + tid;
            int row = f >> 3, ch = f & 7;
            u32x4 v = *(const u32x4*)(xb + (size_t)toks[row] * DIM + k0 + ch * 8);
            *(u32x4*)(As + row * 64 + ((ch ^ (row & 7)) << 3)) = v;
        }
#pragma unroll
        for (int i = 0; i < 2; i++) {
            int f = i * 256 + tid;
            int row = f >> 3, ch = f & 7;
            {
                const float* src = W1 + (size_t)row * DIM + k0 + ch * 8;
                float4v a = *(const float4v*)src, b = *(const float4v*)(src + 4);
                short8 o;
                o[0]=(short)f2bf(a[0]); o[1]=(short)f2bf(a[1]); o[2]=(short)f2bf(a[2]); o[3]=(short)f2bf(a[3]);
                o[4]=(short)f2bf(b[0]); o[5]=(short)f2bf(b[1]); o[6]=(short)f2bf(b[2]); o[7]=(short)f2bf(b[3]);
                *(short8*)(B1s + row * 64 + ((ch ^ (row & 7)) << 3)) = o;
            }
            {
                const float* src = W3 + (size_t)row * DIM + k0 + ch * 8;
                float4v a = *(const float4v*)src, b = *(const float4v*)(src + 4);
                short8 o;
                o[0]=(short)f2bf(a[0]); o[1]=(short)f2bf(a[1]); o[2]=(short)f2bf(a[2]); o[3]=(short)f2bf(a[3]);
                o[4]=(short)f2bf(b[0]); o[5]=(short)f2bf(b[1]); o[6]=(short)f2bf(b[2]); o[7]=(short)f2bf(b[3]);
                *(short8*)(B3s + row * 64 + ((ch ^ (row & 7)) << 3)) = o;
            }
        }
        __syncthreads();
#pragma unroll
        for (int kk = 0; kk < 2; kk++) {
            int kch = kk * 4 + (lane >> 4);
            short8 af[4], b1f[2], b3f[2];
#pragma unroll
            for (int mf = 0; mf < 4; mf++) {
                int r = wm * 64 + mf * 16 + (lane & 15);
                af[mf] = *(const short8*)(As + r * 64 + ((kch ^ (r & 7)) << 3));
            }
#pragma unroll
            for (int nf = 0; nf < 2; nf++) {
                int r = wn * 32 + nf * 16 + (lane & 15);
                b1f[nf] = *(const short8*)(B1s + r * 64 + ((kch ^ (r & 7)) << 3));
                b3f[nf] = *(const short8*)(B3s + r * 64 + ((kch ^ (r & 7)) << 3));
            }
#pragma unroll
            for (int mf = 0; mf < 4; mf++)
#pragma unroll
                for (int nf = 0; nf < 2; nf++) {
                    acc1[mf][nf] = __builtin_amdgcn_mfma_f32_16x16x32_bf16(af[mf], b1f[nf], acc1[mf][nf], 0, 0, 0);
                    acc3[mf][nf] = __builtin_amdgcn_mfma_f32_16x16x32_bf16(af[mf], b3f[nf], acc3[mf][nf], 0, 0, 0);
                }
        }
    }
#pragma unroll
    for (int mf = 0; mf < 4; mf++)
#pragma unroll
        for (int nf = 0; nf < 2; nf++)
#pragma unroll
            for (int r = 0; r < 4; r++) {
                int row = wm * 64 + mf * 16 + ((lane >> 4) << 2) + r;
                int col = wn * 32 + nf * 16 + (lane & 15);
                if (m0 + row < c) {
                    float a = acc1[mf][nf][r];
                    float g = a / (1.f + expf(-a));
                    float v = g * acc3[mf][nf][r];
                    hbuf[(size_t)(gb + m0 + row) * NH + n0 + col] = f2bf(v);
                }
            }
}

__launch_bounds__(256)
__global__ void k_ffn2_fb(const unsigned short* __restrict__ hbuf,
                          const float* __restrict__ w2,
                          const int* __restrict__ cnt, const int* __restrict__ base,
                          const int* __restrict__ tok, const float* __restrict__ tw,
                          float* __restrict__ y) {
    int e  = blockIdx.x >> 4;
    int mt = blockIdx.x & 15;
    int c  = cnt[e];
    int m0 = mt * 128;
    if (m0 >= c) return;
    int gb = base[e];
    int n0 = blockIdx.y * 128;

    __shared__ unsigned short As[128 * 64];
    __shared__ unsigned short Bs[128 * 64];
    __shared__ int   toks[128];
    __shared__ float gws[128];

    int tid = threadIdx.x;
    if (tid < 128) {
        int s = m0 + tid;
        toks[tid] = (s < c) ? tok[gb + s] : 0;
        gws[tid]  = (s < c) ? tw[gb + s] : 0.f;
    }
    int lane = tid & 63, wid = tid >> 6;
    int wm = wid >> 1, wn = wid & 1;

    f32x4 acc[4][4];
#pragma unroll
    for (int i = 0; i < 4; i++)
#pragma unroll
        for (int j = 0; j < 4; j++) acc[i][j] = (f32x4)0.f;

    const float* W2 = w2 + (size_t)e * DIM * NH + (size_t)n0 * NH;

    for (int kt = 0; kt < NH / 64; ++kt) {
        int k0 = kt * 64;
        __syncthreads();
#pragma unroll
        for (int i = 0; i < 4; i++) {
            int f = i * 256 + tid;
            int row = f >> 3, ch = f & 7;
            int rr = m0 + row; rr = (rr < c) ? rr : (c - 1);
            u32x4 v = *(const u32x4*)(hbuf + (size_t)(gb + rr) * NH + k0 + ch * 8);
            *(u32x4*)(As + row * 64 + ((ch ^ (row & 7)) << 3)) = v;
        }
#pragma unroll
        for (int i = 0; i < 4; i++) {
            int f = i * 256 + tid;
            int row = f >> 3, ch = f & 7;
            const float* src = W2 + (size_t)row * NH + k0 + ch * 8;
            float4v a = *(const float4v*)src, b = *(const float4v*)(src + 4);
            short8 o;
            o[0]=(short)f2bf(a[0]); o[1]=(short)f2bf(a[1]); o[2]=(short)f2bf(a[2]); o[3]=(short)f2bf(a[3]);
            o[4]=(short)f2bf(b[0]); o[5]=(short)f2bf(b[1]); o[6]=(short)f2bf(b[2]); o[7]=(short)f2bf(b[3]);
            *(short8*)(Bs + row * 64 + ((ch ^ (row & 7)) << 3)) = o;
        }
        __syncthreads();
#pragma unroll
        for (int kk = 0; kk < 2; kk++) {
            int kch = kk * 4 + (lane >> 4);
            short8 af[4], bf[4];
#pragma unroll
            for (int mf = 0; mf < 4; mf++) {
                int r = wm * 64 + mf * 16 + (lane & 15);
                af[mf] = *(const short8*)(As + r * 64 + ((kch ^ (r & 7)) << 3));
            }
#pragma unroll
            for (int nf = 0; nf < 4; nf++) {
                int r = wn * 64 + nf * 16 + (lane & 15);
                bf[nf] = *(const short8*)(Bs + r * 64 + ((kch ^ (r & 7)) << 3));
            }
#pragma unroll
            for (int mf = 0; mf < 4; mf++)
#pragma unroll
                for (int nf = 0; nf < 4; nf++)
                    acc[mf][nf] = __builtin_amdgcn_mfma_f32_16x16x32_bf16(af[mf], bf[nf], acc[mf][nf], 0, 0, 0);
        }
    }
#pragma unroll
    for (int mf = 0; mf < 4; mf++)
#pragma unroll
        for (int nf = 0; nf < 4; nf++)
#pragma unroll
            for (int r = 0; r < 4; r++) {
                int row = wm * 64 + mf * 16 + ((lane >> 4) << 2) + r;
                int col = wn * 64 + nf * 16 + (lane & 15);
                if (m0 + row < c) {
                    float v = gws[row] * acc[mf][nf][r];
                    atomicAdd(&y[(size_t)toks[row] * DIM + n0 + col], v);
                }
            }
}

// ---------------- launch ----------------
extern "C" void kernel_launch(void* const* d_in, const int* in_sizes, int n_in,
                              void* d_out, int out_size, void* d_ws, size_t ws_size,
                              hipStream_t stream) {
    const float* x  = (const float*)d_in[0];
    const float* gw = (const float*)d_in[1];
    const float* w1 = (const float*)d_in[2];
    const float* w2 = (const float*)d_in[3];
    const float* w3 = (const float*)d_in[4];
    float* y = (float*)d_out;

    char* ws = (char*)d_ws;
    int*   cnt  = (int*)(ws + 0);
    int*   run  = (int*)(ws + 64);
    int*   basep= (int*)(ws + 128);
    int*   tok  = (int*)(ws + 256);
    float* tw   = (float*)(ws + 16640);
    int*   rt_e = (int*)(ws + 33024);
    float* rt_w = (float*)(ws + 49408);
    unsigned short* xb   = (unsigned short*)(ws + 65792);
    unsigned short* hbuf = (unsigned short*)(ws + 8454400);            // 46,137,344 B
    unsigned short* w1b  = (unsigned short*)(ws + 54591744);           // 184,549,376 B
    unsigned short* w3b  = (unsigned short*)(ws + 239141120);          // 184,549,376 B
    unsigned short* w2b  = (unsigned short*)(ws + 423690496);          // 184,549,376 B
    const size_t needed = 608239872ull;

    hipMemsetAsync(ws, 0, 256, stream);
    hipMemsetAsync(d_out, 0, (size_t)out_size * sizeof(float), stream);

    k_cvt<<<(T_TOK * DIM / 8) / 256, 256, 0, stream>>>(x, xb, T_TOK * DIM / 8);
    k_gate<<<T_TOK / 4, 256, 0, stream>>>(x, gw, rt_e, rt_w);
    k_count<<<T_TOK / 256, 256, 0, stream>>>(rt_e, cnt);
    k_base<<<1, 64, 0, stream>>>(cnt, basep);
    k_assign<<<T_TOK / 256, 256, 0, stream>>>(rt_e, rt_w, basep, run, tok, tw);

    if (ws_size >= needed) {
        const int nW = NE * NH * DIM / 8;   // 11,534,336 chunks of 8
        k_cvt<<<nW / 256, 256, 0, stream>>>(w1, w1b, nW);
        k_cvt<<<nW / 256, 256, 0, stream>>>(w3, w3b, nW);
        k_cvt<<<nW / 256, 256, 0, stream>>>(w2, w2b, nW);
        int nwg1 = NE * 16 * (NH / 64);     // 11264
        int nwg2 = NE * 16 * (DIM / 128);   // 2048
        k_ffn1<<<nwg1, 256, 0, stream>>>(xb, w1b, w3b, cnt, basep, tok, hbuf, nwg1);
        k_ffn2<<<nwg2, 256, 0, stream>>>(hbuf, w2b, cnt, basep, tok, tw, y, nwg2);
    } else {
        k_ffn1_fb<<<dim3(NE * 16, NH / 64), 256, 0, stream>>>(xb, w1, w3, cnt, basep, tok, hbuf);
        k_ffn2_fb<<<dim3(NE * 16, DIM / 128), 256, 0, stream>>>(hbuf, w2, cnt, basep, tok, tw, y);
    }
}

// Round 3
// 1229.143 us; speedup vs baseline: 1.7472x; 1.1990x over previous
//
#include <hip/hip_runtime.h>
#include <hip/hip_bf16.h>

#define T_TOK 2048
#define DIM   2048
#define NE    8
#define NH    5632

typedef __attribute__((ext_vector_type(4))) float f32x4;
typedef __attribute__((ext_vector_type(8))) short short8;
typedef __attribute__((ext_vector_type(4))) unsigned int u32x4;
typedef __attribute__((ext_vector_type(4))) float float4v;

__device__ inline unsigned short f2bf(float f) {
    unsigned u = __builtin_bit_cast(unsigned, f);
    u += 0x7fffu + ((u >> 16) & 1u);       // round-to-nearest-even
    return (unsigned short)(u >> 16);
}

__device__ __forceinline__ void glds16(const void* g, void* l) {
    __builtin_amdgcn_global_load_lds((const __attribute__((address_space(1))) void*)g,
                                     (__attribute__((address_space(3))) void*)l, 16, 0, 0);
}

// ---------------- fp32 -> bf16 flat convert (fallback path only) ----------------
__global__ void k_cvt(const float* __restrict__ src, unsigned short* __restrict__ dst, int n8) {
    int i = blockIdx.x * blockDim.x + threadIdx.x;
    if (i >= n8) return;
    const float4v* xv = (const float4v*)src;
    float4v a = xv[2 * i], b = xv[2 * i + 1];
    short8 o;
    o[0] = (short)f2bf(a[0]); o[1] = (short)f2bf(a[1]);
    o[2] = (short)f2bf(a[2]); o[3] = (short)f2bf(a[3]);
    o[4] = (short)f2bf(b[0]); o[5] = (short)f2bf(b[1]);
    o[6] = (short)f2bf(b[2]); o[7] = (short)f2bf(b[3]);
    ((short8*)dst)[i] = o;
}

// ---------------- gating (fp32, one wave per token) ----------------
__global__ void k_gate(const float* __restrict__ x, const float* __restrict__ gw,
                       int* __restrict__ rt_e, float* __restrict__ rt_w) {
    int wid = threadIdx.x >> 6, lane = threadIdx.x & 63;
    int t = blockIdx.x * 4 + wid;
    if (t >= T_TOK) return;
    float acc[NE];
#pragma unroll
    for (int e = 0; e < NE; e++) acc[e] = 0.f;
    const float* xr = x + (size_t)t * DIM;
    for (int d = lane; d < DIM; d += 64) {
        float xv = xr[d];
#pragma unroll
        for (int e = 0; e < NE; e++) acc[e] += xv * gw[e * DIM + d];
    }
#pragma unroll
    for (int e = 0; e < NE; e++) {
        float v = acc[e];
#pragma unroll
        for (int off = 32; off; off >>= 1) v += __shfl_xor(v, off);
        acc[e] = v;
    }
    if (lane == 0) {
        int i0 = 0; float s0 = acc[0];
#pragma unroll
        for (int e = 1; e < NE; e++) if (acc[e] > s0) { s0 = acc[e]; i0 = e; }
        int i1 = -1; float s1 = -1e30f;
#pragma unroll
        for (int e = 0; e < NE; e++) if (e != i0 && acc[e] > s1) { s1 = acc[e]; i1 = e; }
        float w0 = 1.f / (1.f + expf(s1 - s0));
        rt_e[2 * t] = i0; rt_e[2 * t + 1] = i1;
        rt_w[2 * t] = w0; rt_w[2 * t + 1] = 1.f - w0;
    }
}

__global__ void k_count(const int* __restrict__ rt_e, int* __restrict__ cnt) {
    int t = blockIdx.x * blockDim.x + threadIdx.x;
    if (t >= T_TOK) return;
    atomicAdd(&cnt[rt_e[2 * t]], 1);
    atomicAdd(&cnt[rt_e[2 * t + 1]], 1);
}

// exclusive prefix (slot base) + padded-tile prefix (128-row tiles)
__global__ void k_base(const int* __restrict__ cnt, int* __restrict__ base, int* __restrict__ pb) {
    if (threadIdx.x == 0) {
        int s = 0, p = 0;
        for (int e = 0; e < NE; e++) {
            base[e] = s; pb[e] = p;
            s += cnt[e];
            p += ((cnt[e] + 127) >> 7) << 7;
        }
    }
}

__global__ void k_assign(const int* __restrict__ rt_e, const float* __restrict__ rt_w,
                         const int* __restrict__ base, int* __restrict__ run,
                         int* __restrict__ tok, float* __restrict__ tw) {
    int t = blockIdx.x * blockDim.x + threadIdx.x;
    if (t >= T_TOK) return;
#pragma unroll
    for (int k = 0; k < 2; k++) {
        int e = rt_e[2 * t + k];
        int p = atomicAdd(&run[e], 1);
        int g = base[e] + p;
        tok[g] = t;
        tw[g] = rt_w[2 * t + k];
    }
}

// ---------------- weight convert+pack: fp32 [E][N][K] -> bf16 [e][nt][kt][kc8][rowR][8] ----------------
// grid (KT, NT, E), block 256. Wave: 8 rows x 64 k per iter; lane -> (row=base+(l>>3), kc=l&7).
__global__ void k_packw(const float* __restrict__ src, unsigned short* __restrict__ dst,
                        int N, int K, int R, int NT, int KT) {
    int e = blockIdx.z, nt = blockIdx.y, kt = blockIdx.x;
    int lane = threadIdx.x & 63, w = threadIdx.x >> 6;
    int n0 = nt * R, k0 = kt * 64;
    int iters = R >> 5;                 // 32 rows per 4-wave pass
    int blkShorts = R << 6;             // 8*R*8
    unsigned short* db = dst + ((size_t)(e * NT + nt) * KT + kt) * blkShorts;
    const float* sb = src + (size_t)e * N * K;
    int kc = lane & 7;
    for (int it = 0; it < iters; ++it) {
        int rloc = it * 32 + w * 8 + (lane >> 3);
        const float* s = sb + (size_t)(n0 + rloc) * K + k0 + kc * 8;
        float4v a = *(const float4v*)s, b = *(const float4v*)(s + 4);
        short8 o;
        o[0]=(short)f2bf(a[0]); o[1]=(short)f2bf(a[1]); o[2]=(short)f2bf(a[2]); o[3]=(short)f2bf(a[3]);
        o[4]=(short)f2bf(b[0]); o[5]=(short)f2bf(b[1]); o[6]=(short)f2bf(b[2]); o[7]=(short)f2bf(b[3]);
        *(short8*)(db + (size_t)kc * R * 8 + rloc * 8) = o;
    }
}

// ---------------- x gather+convert+pack: [ptile][kt32][kc8][row128][8] ----------------
__global__ void k_xpack(const float* __restrict__ x,
                        const int* __restrict__ cnt, const int* __restrict__ base,
                        const int* __restrict__ pb, const int* __restrict__ tok,
                        unsigned short* __restrict__ xp) {
    int e = blockIdx.z, mt = blockIdx.y, kt = blockIdx.x;
    int c = cnt[e], m0 = mt * 128;
    if (m0 >= c) return;
    int gb = base[e];
    int ptile = (pb[e] >> 7) + mt;
    int lane = threadIdx.x & 63, w = threadIdx.x >> 6;
    int kc = lane & 7;
    unsigned short* db = xp + (size_t)ptile * 262144 + (size_t)kt * 8192;
#pragma unroll
    for (int it = 0; it < 4; ++it) {
        int rloc = it * 32 + w * 8 + (lane >> 3);
        int slot = m0 + rloc;
        int t = tok[gb + (slot < c ? slot : 0)];
        const float* s = x + (size_t)t * DIM + kt * 64 + kc * 8;
        float4v a = *(const float4v*)s, b = *(const float4v*)(s + 4);
        short8 o;
        o[0]=(short)f2bf(a[0]); o[1]=(short)f2bf(a[1]); o[2]=(short)f2bf(a[2]); o[3]=(short)f2bf(a[3]);
        o[4]=(short)f2bf(b[0]); o[5]=(short)f2bf(b[1]); o[6]=(short)f2bf(b[2]); o[7]=(short)f2bf(b[3]);
        *(short8*)(db + kc * 1024 + rloc * 8) = o;
    }
}

// =====================================================================
// GEMM1: h = silu(x@w1^T)*(x@w3^T). 128Mx64N, BK=64, 4 waves, dbuf 2-phase.
// All staging = contiguous 1KB glds16; LDS [kc][row][8] conflict-free reads.
// =====================================================================
__launch_bounds__(256)
__global__ void k_ffn1(const unsigned short* __restrict__ xp,
                       const unsigned short* __restrict__ w1p, const unsigned short* __restrict__ w3p,
                       const int* __restrict__ cnt, const int* __restrict__ pb,
                       unsigned short* __restrict__ hb, int nwg) {
    int bid = blockIdx.x;
    int swz = (bid & 7) * (nwg >> 3) + (bid >> 3);
    int mt = swz & 15;
    int r2 = swz >> 4;
    int nt = r2 % 88;
    int e  = r2 / 88;
    int c  = cnt[e];
    int m0 = mt * 128;
    if (m0 >= c) return;
    int ptile = (pb[e] >> 7) + mt;

    __shared__ unsigned short As[2][8192];   // 16KB per buf: [kc8][row128][8]
    __shared__ unsigned short B1[2][4096];   // 8KB per buf:  [kc8][row64][8]
    __shared__ unsigned short B3[2][4096];

    int tid = threadIdx.x;
    int lane = tid & 63, w = tid >> 6;
    int wm = w >> 1, wn = w & 1;
    int half = w & 1, wh = w >> 1;

    const unsigned short* aB  = xp  + (size_t)ptile * 262144 + half * 512 + lane * 8;
    const unsigned short* b1B = w1p + (size_t)(e * 88 + nt) * 131072 + lane * 8;
    const unsigned short* b3B = w3p + (size_t)(e * 88 + nt) * 131072 + lane * 8;

    f32x4 acc1[4][2], acc3[4][2];
#pragma unroll
    for (int i = 0; i < 4; i++)
#pragma unroll
        for (int j = 0; j < 2; j++) { acc1[i][j] = (f32x4)0.f; acc3[i][j] = (f32x4)0.f; }

    auto STAGE = [&](int b, int kt) {
#pragma unroll
        for (int i = 0; i < 4; i++) {
            int kc = i * 2 + wh;
            glds16(aB + kt * 8192 + kc * 1024, (char*)&As[b][0] + kc * 2048 + half * 1024);
        }
#pragma unroll
        for (int i = 0; i < 2; i++) {
            int kc = i * 4 + w;
            glds16(b1B + kt * 4096 + kc * 512, (char*)&B1[b][0] + kc * 1024);
            glds16(b3B + kt * 4096 + kc * 512, (char*)&B3[b][0] + kc * 1024);
        }
    };

    STAGE(0, 0);
    asm volatile("s_waitcnt vmcnt(0)" ::: "memory");
    __syncthreads();

    int cur = 0;
    for (int kt = 0; kt < 32; ++kt) {
        if (kt + 1 < 32) STAGE(cur ^ 1, kt + 1);
#pragma unroll
        for (int kh = 0; kh < 2; kh++) {
            int kc = kh * 4 + (lane >> 4);
            short8 a[4], b1[2], b3[2];
#pragma unroll
            for (int mf = 0; mf < 4; mf++) {
                int r = wm * 64 + mf * 16 + (lane & 15);
                a[mf] = *(const short8*)(&As[cur][0] + kc * 1024 + r * 8);
            }
#pragma unroll
            for (int nf = 0; nf < 2; nf++) {
                int rb = wn * 32 + nf * 16 + (lane & 15);
                b1[nf] = *(const short8*)(&B1[cur][0] + kc * 512 + rb * 8);
                b3[nf] = *(const short8*)(&B3[cur][0] + kc * 512 + rb * 8);
            }
#pragma unroll
            for (int mf = 0; mf < 4; mf++)
#pragma unroll
                for (int nf = 0; nf < 2; nf++) {
                    acc1[mf][nf] = __builtin_amdgcn_mfma_f32_16x16x32_bf16(a[mf], b1[nf], acc1[mf][nf], 0, 0, 0);
                    acc3[mf][nf] = __builtin_amdgcn_mfma_f32_16x16x32_bf16(a[mf], b3[nf], acc3[mf][nf], 0, 0, 0);
                }
        }
        asm volatile("s_waitcnt vmcnt(0)" ::: "memory");
        __syncthreads();
        cur ^= 1;
    }

    // epilogue: h -> packed hbufp [ptile][kt_h=nt][kc][row][8]
    unsigned short* hT = hb + ((size_t)ptile * 88 + nt) * 8192;
#pragma unroll
    for (int mf = 0; mf < 4; mf++)
#pragma unroll
        for (int nf = 0; nf < 2; nf++)
#pragma unroll
            for (int r = 0; r < 4; r++) {
                int row = wm * 64 + mf * 16 + ((lane >> 4) << 2) + r;
                int col = wn * 32 + nf * 16 + (lane & 15);
                if (m0 + row < c) {
                    float a = acc1[mf][nf][r];
                    float g = a / (1.f + expf(-a));
                    float v = g * acc3[mf][nf][r];
                    hT[(col >> 3) * 1024 + row * 8 + (col & 7)] = f2bf(v);
                }
            }
}

// =====================================================================
// GEMM2: y[t] += gate_w * (h @ w2^T). 128Mx128N, BK=64, 4 waves, dbuf 2-phase.
// =====================================================================
__launch_bounds__(256)
__global__ void k_ffn2(const unsigned short* __restrict__ hb,
                       const unsigned short* __restrict__ w2p,
                       const int* __restrict__ cnt, const int* __restrict__ base,
                       const int* __restrict__ pb,
                       const int* __restrict__ tok, const float* __restrict__ tw,
                       float* __restrict__ y, int nwg) {
    int bid = blockIdx.x;
    int swz = (bid & 7) * (nwg >> 3) + (bid >> 3);
    int mt = swz & 15;
    int r2 = swz >> 4;
    int nt = r2 & 15;
    int e  = r2 >> 4;
    int c  = cnt[e];
    int m0 = mt * 128;
    if (m0 >= c) return;
    int gb = base[e];
    int ptile = (pb[e] >> 7) + mt;
    int n0 = nt * 128;

    __shared__ unsigned short As[2][8192];
    __shared__ unsigned short Bs[2][8192];
    __shared__ int   toks[128];
    __shared__ float gws[128];

    int tid = threadIdx.x;
    if (tid < 128) {
        int s = m0 + tid;
        toks[tid] = (s < c) ? tok[gb + s] : 0;
        gws[tid]  = (s < c) ? tw[gb + s] : 0.f;
    }

    int lane = tid & 63, w = tid >> 6;
    int wm = w >> 1, wn = w & 1;
    int half = w & 1, wh = w >> 1;

    const unsigned short* aB = hb  + (size_t)ptile * 720896 + half * 512 + lane * 8;       // 88*8192
    const unsigned short* bB = w2p + (size_t)(e * 16 + nt) * 720896 + half * 512 + lane * 8;

    f32x4 acc[4][4];
#pragma unroll
    for (int i = 0; i < 4; i++)
#pragma unroll
        for (int j = 0; j < 4; j++) acc[i][j] = (f32x4)0.f;

    auto STAGE = [&](int b, int kt) {
#pragma unroll
        for (int i = 0; i < 4; i++) {
            int kc = i * 2 + wh;
            glds16(aB + kt * 8192 + kc * 1024, (char*)&As[b][0] + kc * 2048 + half * 1024);
            glds16(bB + kt * 8192 + kc * 1024, (char*)&Bs[b][0] + kc * 2048 + half * 1024);
        }
    };

    STAGE(0, 0);
    asm volatile("s_waitcnt vmcnt(0)" ::: "memory");
    __syncthreads();

    int cur = 0;
    for (int kt = 0; kt < 88; ++kt) {
        if (kt + 1 < 88) STAGE(cur ^ 1, kt + 1);
#pragma unroll
        for (int kh = 0; kh < 2; kh++) {
            int kc = kh * 4 + (lane >> 4);
            short8 a[4], b[4];
#pragma unroll
            for (int mf = 0; mf < 4; mf++) {
                int r = wm * 64 + mf * 16 + (lane & 15);
                a[mf] = *(const short8*)(&As[cur][0] + kc * 1024 + r * 8);
            }
#pragma unroll
            for (int nf = 0; nf < 4; nf++) {
                int rb = wn * 64 + nf * 16 + (lane & 15);
                b[nf] = *(const short8*)(&Bs[cur][0] + kc * 1024 + rb * 8);
            }
#pragma unroll
            for (int mf = 0; mf < 4; mf++)
#pragma unroll
                for (int nf = 0; nf < 4; nf++)
                    acc[mf][nf] = __builtin_amdgcn_mfma_f32_16x16x32_bf16(a[mf], b[nf], acc[mf][nf], 0, 0, 0);
        }
        asm volatile("s_waitcnt vmcnt(0)" ::: "memory");
        __syncthreads();
        cur ^= 1;
    }

#pragma unroll
    for (int mf = 0; mf < 4; mf++)
#pragma unroll
        for (int nf = 0; nf < 4; nf++)
#pragma unroll
            for (int r = 0; r < 4; r++) {
                int row = wm * 64 + mf * 16 + ((lane >> 4) << 2) + r;
                int col = wn * 64 + nf * 16 + (lane & 15);
                if (m0 + row < c) {
                    float v = gws[row] * acc[mf][nf][r];
                    atomicAdd(&y[(size_t)toks[row] * DIM + n0 + col], v);
                }
            }
}

// =====================================================================
// FALLBACK (round-0 style): fp32 weights converted in-loop
// =====================================================================
__launch_bounds__(256)
__global__ void k_ffn1_fb(const unsigned short* __restrict__ xb,
                          const float* __restrict__ w1, const float* __restrict__ w3,
                          const int* __restrict__ cnt, const int* __restrict__ base,
                          const int* __restrict__ tok, unsigned short* __restrict__ hbuf) {
    int e  = blockIdx.x >> 4;
    int mt = blockIdx.x & 15;
    int c  = cnt[e];
    int m0 = mt * 128;
    if (m0 >= c) return;
    int gb = base[e];
    int n0 = blockIdx.y * 64;

    __shared__ unsigned short As[128 * 64];
    __shared__ unsigned short B1s[64 * 64];
    __shared__ unsigned short B3s[64 * 64];
    __shared__ int toks[128];

    int tid = threadIdx.x;
    if (tid < 128) {
        int s = m0 + tid;
        toks[tid] = (s < c) ? tok[gb + s] : tok[gb];
    }
    int lane = tid & 63, wid = tid >> 6;
    int wm = wid >> 1, wn = wid & 1;

    f32x4 acc1[4][2], acc3[4][2];
#pragma unroll
    for (int i = 0; i < 4; i++)
#pragma unroll
        for (int j = 0; j < 2; j++) { acc1[i][j] = (f32x4)0.f; acc3[i][j] = (f32x4)0.f; }

    const float* W1 = w1 + (size_t)e * NH * DIM + (size_t)n0 * DIM;
    const float* W3 = w3 + (size_t)e * NH * DIM + (size_t)n0 * DIM;

    for (int kt = 0; kt < DIM / 64; ++kt) {
        int k0 = kt * 64;
        __syncthreads();
#pragma unroll
        for (int i = 0; i < 4; i++) {
            int f = i * 256 + tid;
            int row = f >> 3, ch = f & 7;
            u32x4 v = *(const u32x4*)(xb + (size_t)toks[row] * DIM + k0 + ch * 8);
            *(u32x4*)(As + row * 64 + ((ch ^ (row & 7)) << 3)) = v;
        }
#pragma unroll
        for (int i = 0; i < 2; i++) {
            int f = i * 256 + tid;
            int row = f >> 3, ch = f & 7;
            {
                const float* src = W1 + (size_t)row * DIM + k0 + ch * 8;
                float4v a = *(const float4v*)src, b = *(const float4v*)(src + 4);
                short8 o;
                o[0]=(short)f2bf(a[0]); o[1]=(short)f2bf(a[1]); o[2]=(short)f2bf(a[2]); o[3]=(short)f2bf(a[3]);
                o[4]=(short)f2bf(b[0]); o[5]=(short)f2bf(b[1]); o[6]=(short)f2bf(b[2]); o[7]=(short)f2bf(b[3]);
                *(short8*)(B1s + row * 64 + ((ch ^ (row & 7)) << 3)) = o;
            }
            {
                const float* src = W3 + (size_t)row * DIM + k0 + ch * 8;
                float4v a = *(const float4v*)src, b = *(const float4v*)(src + 4);
                short8 o;
                o[0]=(short)f2bf(a[0]); o[1]=(short)f2bf(a[1]); o[2]=(short)f2bf(a[2]); o[3]=(short)f2bf(a[3]);
                o[4]=(short)f2bf(b[0]); o[5]=(short)f2bf(b[1]); o[6]=(short)f2bf(b[2]); o[7]=(short)f2bf(b[3]);
                *(short8*)(B3s + row * 64 + ((ch ^ (row & 7)) << 3)) = o;
            }
        }
        __syncthreads();
#pragma unroll
        for (int kk = 0; kk < 2; kk++) {
            int kch = kk * 4 + (lane >> 4);
            short8 af[4], b1f[2], b3f[2];
#pragma unroll
            for (int mf = 0; mf < 4; mf++) {
                int r = wm * 64 + mf * 16 + (lane & 15);
                af[mf] = *(const short8*)(As + r * 64 + ((kch ^ (r & 7)) << 3));
            }
#pragma unroll
            for (int nf = 0; nf < 2; nf++) {
                int r = wn * 32 + nf * 16 + (lane & 15);
                b1f[nf] = *(const short8*)(B1s + r * 64 + ((kch ^ (r & 7)) << 3));
                b3f[nf] = *(const short8*)(B3s + r * 64 + ((kch ^ (r & 7)) << 3));
            }
#pragma unroll
            for (int mf = 0; mf < 4; mf++)
#pragma unroll
                for (int nf = 0; nf < 2; nf++) {
                    acc1[mf][nf] = __builtin_amdgcn_mfma_f32_16x16x32_bf16(af[mf], b1f[nf], acc1[mf][nf], 0, 0, 0);
                    acc3[mf][nf] = __builtin_amdgcn_mfma_f32_16x16x32_bf16(af[mf], b3f[nf], acc3[mf][nf], 0, 0, 0);
                }
        }
    }
#pragma unroll
    for (int mf = 0; mf < 4; mf++)
#pragma unroll
        for (int nf = 0; nf < 2; nf++)
#pragma unroll
            for (int r = 0; r < 4; r++) {
                int row = wm * 64 + mf * 16 + ((lane >> 4) << 2) + r;
                int col = wn * 32 + nf * 16 + (lane & 15);
                if (m0 + row < c) {
                    float a = acc1[mf][nf][r];
                    float g = a / (1.f + expf(-a));
                    float v = g * acc3[mf][nf][r];
                    hbuf[(size_t)(gb + m0 + row) * NH + n0 + col] = f2bf(v);
                }
            }
}

__launch_bounds__(256)
__global__ void k_ffn2_fb(const unsigned short* __restrict__ hbuf,
                          const float* __restrict__ w2,
                          const int* __restrict__ cnt, const int* __restrict__ base,
                          const int* __restrict__ tok, const float* __restrict__ tw,
                          float* __restrict__ y) {
    int e  = blockIdx.x >> 4;
    int mt = blockIdx.x & 15;
    int c  = cnt[e];
    int m0 = mt * 128;
    if (m0 >= c) return;
    int gb = base[e];
    int n0 = blockIdx.y * 128;

    __shared__ unsigned short As[128 * 64];
    __shared__ unsigned short Bs[128 * 64];
    __shared__ int   toks[128];
    __shared__ float gws[128];

    int tid = threadIdx.x;
    if (tid < 128) {
        int s = m0 + tid;
        toks[tid] = (s < c) ? tok[gb + s] : 0;
        gws[tid]  = (s < c) ? tw[gb + s] : 0.f;
    }
    int lane = tid & 63, wid = tid >> 6;
    int wm = wid >> 1, wn = wid & 1;

    f32x4 acc[4][4];
#pragma unroll
    for (int i = 0; i < 4; i++)
#pragma unroll
        for (int j = 0; j < 4; j++) acc[i][j] = (f32x4)0.f;

    const float* W2 = w2 + (size_t)e * DIM * NH + (size_t)n0 * NH;

    for (int kt = 0; kt < NH / 64; ++kt) {
        int k0 = kt * 64;
        __syncthreads();
#pragma unroll
        for (int i = 0; i < 4; i++) {
            int f = i * 256 + tid;
            int row = f >> 3, ch = f & 7;
            int rr = m0 + row; rr = (rr < c) ? rr : (c - 1);
            u32x4 v = *(const u32x4*)(hbuf + (size_t)(gb + rr) * NH + k0 + ch * 8);
            *(u32x4*)(As + row * 64 + ((ch ^ (row & 7)) << 3)) = v;
        }
#pragma unroll
        for (int i = 0; i < 4; i++) {
            int f = i * 256 + tid;
            int row = f >> 3, ch = f & 7;
            const float* src = W2 + (size_t)row * NH + k0 + ch * 8;
            float4v a = *(const float4v*)src, b = *(const float4v*)(src + 4);
            short8 o;
            o[0]=(short)f2bf(a[0]); o[1]=(short)f2bf(a[1]); o[2]=(short)f2bf(a[2]); o[3]=(short)f2bf(a[3]);
            o[4]=(short)f2bf(b[0]); o[5]=(short)f2bf(b[1]); o[6]=(short)f2bf(b[2]); o[7]=(short)f2bf(b[3]);
            *(short8*)(Bs + row * 64 + ((ch ^ (row & 7)) << 3)) = o;
        }
        __syncthreads();
#pragma unroll
        for (int kk = 0; kk < 2; kk++) {
            int kch = kk * 4 + (lane >> 4);
            short8 af[4], bf[4];
#pragma unroll
            for (int mf = 0; mf < 4; mf++) {
                int r = wm * 64 + mf * 16 + (lane & 15);
                af[mf] = *(const short8*)(As + r * 64 + ((kch ^ (r & 7)) << 3));
            }
#pragma unroll
            for (int nf = 0; nf < 4; nf++) {
                int r = wn * 64 + nf * 16 + (lane & 15);
                bf[nf] = *(const short8*)(Bs + r * 64 + ((kch ^ (r & 7)) << 3));
            }
#pragma unroll
            for (int mf = 0; mf < 4; mf++)
#pragma unroll
                for (int nf = 0; nf < 4; nf++)
                    acc[mf][nf] = __builtin_amdgcn_mfma_f32_16x16x32_bf16(af[mf], bf[nf], acc[mf][nf], 0, 0, 0);
        }
    }
#pragma unroll
    for (int mf = 0; mf < 4; mf++)
#pragma unroll
        for (int nf = 0; nf < 4; nf++)
#pragma unroll
            for (int r = 0; r < 4; r++) {
                int row = wm * 64 + mf * 16 + ((lane >> 4) << 2) + r;
                int col = wn * 64 + nf * 16 + (lane & 15);
                if (m0 + row < c) {
                    float v = gws[row] * acc[mf][nf][r];
                    atomicAdd(&y[(size_t)toks[row] * DIM + n0 + col], v);
                }
            }
}

// ---------------- launch ----------------
extern "C" void kernel_launch(void* const* d_in, const int* in_sizes, int n_in,
                              void* d_out, int out_size, void* d_ws, size_t ws_size,
                              hipStream_t stream) {
    const float* x  = (const float*)d_in[0];
    const float* gw = (const float*)d_in[1];
    const float* w1 = (const float*)d_in[2];
    const float* w2 = (const float*)d_in[3];
    const float* w3 = (const float*)d_in[4];
    float* y = (float*)d_out;

    char* ws = (char*)d_ws;
    int*   cnt  = (int*)(ws + 0);
    int*   run  = (int*)(ws + 64);
    int*   basep= (int*)(ws + 128);
    int*   pb   = (int*)(ws + 192);
    int*   tok  = (int*)(ws + 256);
    float* tw   = (float*)(ws + 16640);
    int*   rt_e = (int*)(ws + 33024);
    float* rt_w = (float*)(ws + 49408);
    unsigned short* xp    = (unsigned short*)(ws + 66048);       // 20,971,520 B (also xb in fallback)
    unsigned short* hbufp = (unsigned short*)(ws + 21037568);    // 57,671,680 B (also hbuf flat in fallback)
    unsigned short* w1p   = (unsigned short*)(ws + 78709248);    // 184,549,376 B
    unsigned short* w3p   = (unsigned short*)(ws + 263258624);   // 184,549,376 B
    unsigned short* w2p   = (unsigned short*)(ws + 447808000);   // 184,549,376 B
    const size_t needed = 632357376ull;

    hipMemsetAsync(ws, 0, 256, stream);
    hipMemsetAsync(d_out, 0, (size_t)out_size * sizeof(float), stream);

    k_gate<<<T_TOK / 4, 256, 0, stream>>>(x, gw, rt_e, rt_w);
    k_count<<<T_TOK / 256, 256, 0, stream>>>(rt_e, cnt);
    k_base<<<1, 64, 0, stream>>>(cnt, basep, pb);
    k_assign<<<T_TOK / 256, 256, 0, stream>>>(rt_e, rt_w, basep, run, tok, tw);

    if (ws_size >= needed) {
        // convert+pack weights into GEMM-native tiled layouts
        k_packw<<<dim3(32, 88, NE), 256, 0, stream>>>(w1, w1p, NH, DIM, 64, 88, 32);
        k_packw<<<dim3(32, 88, NE), 256, 0, stream>>>(w3, w3p, NH, DIM, 64, 88, 32);
        k_packw<<<dim3(88, 16, NE), 256, 0, stream>>>(w2, w2p, DIM, NH, 128, 16, 88);
        k_xpack<<<dim3(32, 16, NE), 256, 0, stream>>>(x, cnt, basep, pb, tok, xp);
        int nwg1 = NE * 16 * 88;     // 11264
        int nwg2 = NE * 16 * 16;     // 2048
        k_ffn1<<<nwg1, 256, 0, stream>>>(xp, w1p, w3p, cnt, pb, hbufp, nwg1);
        k_ffn2<<<nwg2, 256, 0, stream>>>(hbufp, w2p, cnt, basep, pb, tok, tw, y, nwg2);
    } else {
        k_cvt<<<(T_TOK * DIM / 8) / 256, 256, 0, stream>>>(x, xp, T_TOK * DIM / 8);
        k_ffn1_fb<<<dim3(NE * 16, NH / 64), 256, 0, stream>>>(xp, w1, w3, cnt, basep, tok, hbufp);
        k_ffn2_fb<<<dim3(NE * 16, DIM / 128), 256, 0, stream>>>(hbufp, w2, cnt, basep, tok, tw, y);
    }
}

// Round 4
// 1156.382 us; speedup vs baseline: 1.8571x; 1.0629x over previous
//
#include <hip/hip_runtime.h>
#include <hip/hip_bf16.h>

#define T_TOK 2048
#define DIM   2048
#define NE    8
#define NH    5632

typedef __attribute__((ext_vector_type(4))) float f32x4;
typedef __attribute__((ext_vector_type(8))) short short8;
typedef __attribute__((ext_vector_type(4))) unsigned int u32x4;
typedef __attribute__((ext_vector_type(4))) float float4v;

__device__ inline unsigned short f2bf(float f) {
    unsigned u = __builtin_bit_cast(unsigned, f);
    u += 0x7fffu + ((u >> 16) & 1u);       // round-to-nearest-even
    return (unsigned short)(u >> 16);
}

__device__ __forceinline__ void glds16(const void* g, void* l) {
    __builtin_amdgcn_global_load_lds((const __attribute__((address_space(1))) void*)g,
                                     (__attribute__((address_space(3))) void*)l, 16, 0, 0);
}

// ---------------- fp32 -> bf16 flat convert (fallback path only) ----------------
__global__ void k_cvt(const float* __restrict__ src, unsigned short* __restrict__ dst, int n8) {
    int i = blockIdx.x * blockDim.x + threadIdx.x;
    if (i >= n8) return;
    const float4v* xv = (const float4v*)src;
    float4v a = xv[2 * i], b = xv[2 * i + 1];
    short8 o;
    o[0] = (short)f2bf(a[0]); o[1] = (short)f2bf(a[1]);
    o[2] = (short)f2bf(a[2]); o[3] = (short)f2bf(a[3]);
    o[4] = (short)f2bf(b[0]); o[5] = (short)f2bf(b[1]);
    o[6] = (short)f2bf(b[2]); o[7] = (short)f2bf(b[3]);
    ((short8*)dst)[i] = o;
}

// ---------------- gating + count fused (fp32, one wave per token) ----------------
__global__ void k_gate(const float* __restrict__ x, const float* __restrict__ gw,
                       int* __restrict__ rt_e, float* __restrict__ rt_w, int* __restrict__ cnt) {
    int wid = threadIdx.x >> 6, lane = threadIdx.x & 63;
    int t = blockIdx.x * 4 + wid;
    if (t >= T_TOK) return;
    float acc[NE];
#pragma unroll
    for (int e = 0; e < NE; e++) acc[e] = 0.f;
    const float* xr = x + (size_t)t * DIM;
    for (int d = lane; d < DIM; d += 64) {
        float xv = xr[d];
#pragma unroll
        for (int e = 0; e < NE; e++) acc[e] += xv * gw[e * DIM + d];
    }
#pragma unroll
    for (int e = 0; e < NE; e++) {
        float v = acc[e];
#pragma unroll
        for (int off = 32; off; off >>= 1) v += __shfl_xor(v, off);
        acc[e] = v;
    }
    if (lane == 0) {
        int i0 = 0; float s0 = acc[0];
#pragma unroll
        for (int e = 1; e < NE; e++) if (acc[e] > s0) { s0 = acc[e]; i0 = e; }
        int i1 = -1; float s1 = -1e30f;
#pragma unroll
        for (int e = 0; e < NE; e++) if (e != i0 && acc[e] > s1) { s1 = acc[e]; i1 = e; }
        float w0 = 1.f / (1.f + expf(s1 - s0));
        rt_e[2 * t] = i0; rt_e[2 * t + 1] = i1;
        rt_w[2 * t] = w0; rt_w[2 * t + 1] = 1.f - w0;
        atomicAdd(&cnt[i0], 1);
        atomicAdd(&cnt[i1], 1);
    }
}

// exclusive prefix (slot base) + padded-tile prefix (128-row tiles)
__global__ void k_base(const int* __restrict__ cnt, int* __restrict__ base, int* __restrict__ pb) {
    if (threadIdx.x == 0) {
        int s = 0, p = 0;
        for (int e = 0; e < NE; e++) {
            base[e] = s; pb[e] = p;
            s += cnt[e];
            p += ((cnt[e] + 127) >> 7) << 7;
        }
    }
}

__global__ void k_assign(const int* __restrict__ rt_e, const float* __restrict__ rt_w,
                         const int* __restrict__ base, int* __restrict__ run,
                         int* __restrict__ tok, float* __restrict__ tw) {
    int t = blockIdx.x * blockDim.x + threadIdx.x;
    if (t >= T_TOK) return;
#pragma unroll
    for (int k = 0; k < 2; k++) {
        int e = rt_e[2 * t + k];
        int p = atomicAdd(&run[e], 1);
        int g = base[e] + p;
        tok[g] = t;
        tw[g] = rt_w[2 * t + k];
    }
}

// ---------------- weight convert+pack w1 & w3: fp32 [E][NH][DIM] -> [e][nt88][kt32][kc8][row64][8] ----------------
__global__ void k_packw13(const float* __restrict__ w1, const float* __restrict__ w3,
                          unsigned short* __restrict__ w1p, unsigned short* __restrict__ w3p) {
    int z = blockIdx.z;                       // 0..15
    const float* src = (z < 8) ? w1 : w3;
    unsigned short* dst = (z < 8) ? w1p : w3p;
    int e = z & 7, nt = blockIdx.y, kt = blockIdx.x;
    int lane = threadIdx.x & 63, w = threadIdx.x >> 6;
    int kc = lane & 7;
    const float* sb = src + (size_t)e * NH * DIM;
    unsigned short* db = dst + ((size_t)(e * 88 + nt) * 32 + kt) * 4096;
#pragma unroll
    for (int it = 0; it < 2; ++it) {
        int rloc = it * 32 + w * 8 + (lane >> 3);
        const float* s = sb + (size_t)(nt * 64 + rloc) * DIM + kt * 64 + kc * 8;
        float4v a = *(const float4v*)s, b = *(const float4v*)(s + 4);
        short8 o;
        o[0]=(short)f2bf(a[0]); o[1]=(short)f2bf(a[1]); o[2]=(short)f2bf(a[2]); o[3]=(short)f2bf(a[3]);
        o[4]=(short)f2bf(b[0]); o[5]=(short)f2bf(b[1]); o[6]=(short)f2bf(b[2]); o[7]=(short)f2bf(b[3]);
        *(short8*)(db + kc * 512 + rloc * 8) = o;
    }
}

// ---------------- weight convert+pack w2: fp32 [E][DIM][NH] -> [e][nt16][kt88][kc8][row128][8] ----------------
__global__ void k_packw2(const float* __restrict__ w2, unsigned short* __restrict__ w2p) {
    int e = blockIdx.z, nt = blockIdx.y, kt = blockIdx.x;   // (88, 16, 8)
    int lane = threadIdx.x & 63, w = threadIdx.x >> 6;
    int kc = lane & 7;
    const float* sb = w2 + (size_t)e * DIM * NH;
    unsigned short* db = w2p + ((size_t)(e * 16 + nt) * 88 + kt) * 8192;
#pragma unroll
    for (int it = 0; it < 4; ++it) {
        int rloc = it * 32 + w * 8 + (lane >> 3);
        const float* s = sb + (size_t)(nt * 128 + rloc) * NH + kt * 64 + kc * 8;
        float4v a = *(const float4v*)s, b = *(const float4v*)(s + 4);
        short8 o;
        o[0]=(short)f2bf(a[0]); o[1]=(short)f2bf(a[1]); o[2]=(short)f2bf(a[2]); o[3]=(short)f2bf(a[3]);
        o[4]=(short)f2bf(b[0]); o[5]=(short)f2bf(b[1]); o[6]=(short)f2bf(b[2]); o[7]=(short)f2bf(b[3]);
        *(short8*)(db + kc * 1024 + rloc * 8) = o;
    }
}

// ---------------- x gather+convert+pack: [ptile][kt32][kc8][row128][8] ----------------
__global__ void k_xpack(const float* __restrict__ x,
                        const int* __restrict__ cnt, const int* __restrict__ base,
                        const int* __restrict__ pb, const int* __restrict__ tok,
                        unsigned short* __restrict__ xp) {
    int e = blockIdx.z, mt = blockIdx.y, kt = blockIdx.x;
    int c = cnt[e], m0 = mt * 128;
    if (m0 >= c) return;
    int gb = base[e];
    int ptile = (pb[e] >> 7) + mt;
    int lane = threadIdx.x & 63, w = threadIdx.x >> 6;
    int kc = lane & 7;
    unsigned short* db = xp + (size_t)ptile * 262144 + (size_t)kt * 8192;
#pragma unroll
    for (int it = 0; it < 4; ++it) {
        int rloc = it * 32 + w * 8 + (lane >> 3);
        int slot = m0 + rloc;
        int t = tok[gb + (slot < c ? slot : 0)];
        const float* s = x + (size_t)t * DIM + kt * 64 + kc * 8;
        float4v a = *(const float4v*)s, b = *(const float4v*)(s + 4);
        short8 o;
        o[0]=(short)f2bf(a[0]); o[1]=(short)f2bf(a[1]); o[2]=(short)f2bf(a[2]); o[3]=(short)f2bf(a[3]);
        o[4]=(short)f2bf(b[0]); o[5]=(short)f2bf(b[1]); o[6]=(short)f2bf(b[2]); o[7]=(short)f2bf(b[3]);
        *(short8*)(db + kc * 1024 + rloc * 8) = o;
    }
}

// =====================================================================
// GEMM1: h = silu(x@w1^T)*(x@w3^T). 128Mx64N, BK=64, 4 waves.
// Depth-2 pipeline, counted vmcnt(8), raw s_barrier (no implicit drain).
// =====================================================================
__launch_bounds__(256)
__global__ void k_ffn1(const unsigned short* __restrict__ xp,
                       const unsigned short* __restrict__ w1p, const unsigned short* __restrict__ w3p,
                       const int* __restrict__ cnt, const int* __restrict__ pb,
                       unsigned short* __restrict__ hb, int nwg) {
    int bid = blockIdx.x;
    int swz = (bid & 7) * (nwg >> 3) + (bid >> 3);
    int mt = swz & 15;
    int r2 = swz >> 4;
    int nt = r2 % 88;
    int e  = r2 / 88;
    int c  = cnt[e];
    int m0 = mt * 128;
    if (m0 >= c) return;
    int ptile = (pb[e] >> 7) + mt;

    __shared__ unsigned short As[2][8192];   // [kc8][row128][8]
    __shared__ unsigned short B1[2][4096];   // [kc8][row64][8]
    __shared__ unsigned short B3[2][4096];

    int tid = threadIdx.x;
    int lane = tid & 63, w = tid >> 6;
    int wm = w >> 1, wn = w & 1;
    int half = w & 1, wh = w >> 1;

    const unsigned short* aB  = xp  + (size_t)ptile * 262144 + half * 512 + lane * 8;
    const unsigned short* b1B = w1p + (size_t)(e * 88 + nt) * 131072 + lane * 8;
    const unsigned short* b3B = w3p + (size_t)(e * 88 + nt) * 131072 + lane * 8;

    f32x4 acc1[4][2], acc3[4][2];
#pragma unroll
    for (int i = 0; i < 4; i++)
#pragma unroll
        for (int j = 0; j < 2; j++) { acc1[i][j] = (f32x4)0.f; acc3[i][j] = (f32x4)0.f; }

    auto STAGE = [&](int b, int kt) {       // 8 glds16 per thread
#pragma unroll
        for (int i = 0; i < 4; i++) {
            int kc = i * 2 + wh;
            glds16(aB + kt * 8192 + kc * 1024, (char*)&As[b][0] + kc * 2048 + half * 1024);
        }
#pragma unroll
        for (int i = 0; i < 2; i++) {
            int kc = i * 4 + w;
            glds16(b1B + kt * 4096 + kc * 512, (char*)&B1[b][0] + kc * 1024);
            glds16(b3B + kt * 4096 + kc * 512, (char*)&B3[b][0] + kc * 1024);
        }
    };

    STAGE(0, 0);
    STAGE(1, 1);
    int cur = 0;
    for (int kt = 0; kt < 32; ++kt) {
        if (kt < 31) asm volatile("s_waitcnt vmcnt(8)" ::: "memory");
        else         asm volatile("s_waitcnt vmcnt(0)" ::: "memory");
        __builtin_amdgcn_s_barrier();
#pragma unroll
        for (int kh = 0; kh < 2; kh++) {
            int kc = kh * 4 + (lane >> 4);
            short8 a[4], b1[2], b3[2];
#pragma unroll
            for (int mf = 0; mf < 4; mf++) {
                int r = wm * 64 + mf * 16 + (lane & 15);
                a[mf] = *(const short8*)(&As[cur][0] + kc * 1024 + r * 8);
            }
#pragma unroll
            for (int nf = 0; nf < 2; nf++) {
                int rb = wn * 32 + nf * 16 + (lane & 15);
                b1[nf] = *(const short8*)(&B1[cur][0] + kc * 512 + rb * 8);
                b3[nf] = *(const short8*)(&B3[cur][0] + kc * 512 + rb * 8);
            }
            __builtin_amdgcn_s_setprio(1);
#pragma unroll
            for (int mf = 0; mf < 4; mf++)
#pragma unroll
                for (int nf = 0; nf < 2; nf++) {
                    acc1[mf][nf] = __builtin_amdgcn_mfma_f32_16x16x32_bf16(a[mf], b1[nf], acc1[mf][nf], 0, 0, 0);
                    acc3[mf][nf] = __builtin_amdgcn_mfma_f32_16x16x32_bf16(a[mf], b3[nf], acc3[mf][nf], 0, 0, 0);
                }
            __builtin_amdgcn_s_setprio(0);
        }
        asm volatile("s_waitcnt lgkmcnt(0)" ::: "memory");
        __builtin_amdgcn_s_barrier();
        if (kt + 2 < 32) STAGE(cur, kt + 2);
        cur ^= 1;
    }

    // epilogue: h -> packed hbufp [ptile][kt_h=nt][kc][row][8]
    unsigned short* hT = hb + ((size_t)ptile * 88 + nt) * 8192;
#pragma unroll
    for (int mf = 0; mf < 4; mf++)
#pragma unroll
        for (int nf = 0; nf < 2; nf++)
#pragma unroll
            for (int r = 0; r < 4; r++) {
                int row = wm * 64 + mf * 16 + ((lane >> 4) << 2) + r;
                int col = wn * 32 + nf * 16 + (lane & 15);
                if (m0 + row < c) {
                    float a = acc1[mf][nf][r];
                    float g = a / (1.f + expf(-a));
                    float v = g * acc3[mf][nf][r];
                    hT[(col >> 3) * 1024 + row * 8 + (col & 7)] = f2bf(v);
                }
            }
}

// =====================================================================
// GEMM2: y[t] += gate_w * (h @ w2^T). 128Mx128N, BK=64, 4 waves.
// Same depth-2 counted-vmcnt pipeline.
// =====================================================================
__launch_bounds__(256)
__global__ void k_ffn2(const unsigned short* __restrict__ hb,
                       const unsigned short* __restrict__ w2p,
                       const int* __restrict__ cnt, const int* __restrict__ base,
                       const int* __restrict__ pb,
                       const int* __restrict__ tok, const float* __restrict__ tw,
                       float* __restrict__ y, int nwg) {
    int bid = blockIdx.x;
    int swz = (bid & 7) * (nwg >> 3) + (bid >> 3);
    int mt = swz & 15;
    int r2 = swz >> 4;
    int nt = r2 & 15;
    int e  = r2 >> 4;
    int c  = cnt[e];
    int m0 = mt * 128;
    if (m0 >= c) return;
    int gb = base[e];
    int ptile = (pb[e] >> 7) + mt;
    int n0 = nt * 128;

    __shared__ unsigned short As[2][8192];
    __shared__ unsigned short Bs[2][8192];
    __shared__ int   toks[128];
    __shared__ float gws[128];

    int tid = threadIdx.x;
    if (tid < 128) {
        int s = m0 + tid;
        toks[tid] = (s < c) ? tok[gb + s] : 0;
        gws[tid]  = (s < c) ? tw[gb + s] : 0.f;
    }

    int lane = tid & 63, w = tid >> 6;
    int wm = w >> 1, wn = w & 1;
    int half = w & 1, wh = w >> 1;

    const unsigned short* aB = hb  + (size_t)ptile * 720896 + half * 512 + lane * 8;
    const unsigned short* bB = w2p + (size_t)(e * 16 + nt) * 720896 + half * 512 + lane * 8;

    f32x4 acc[4][4];
#pragma unroll
    for (int i = 0; i < 4; i++)
#pragma unroll
        for (int j = 0; j < 4; j++) acc[i][j] = (f32x4)0.f;

    auto STAGE = [&](int b, int kt) {       // 8 glds16 per thread
#pragma unroll
        for (int i = 0; i < 4; i++) {
            int kc = i * 2 + wh;
            glds16(aB + kt * 8192 + kc * 1024, (char*)&As[b][0] + kc * 2048 + half * 1024);
            glds16(bB + kt * 8192 + kc * 1024, (char*)&Bs[b][0] + kc * 2048 + half * 1024);
        }
    };

    STAGE(0, 0);
    STAGE(1, 1);
    int cur = 0;
    for (int kt = 0; kt < 88; ++kt) {
        if (kt < 87) asm volatile("s_waitcnt vmcnt(8)" ::: "memory");
        else         asm volatile("s_waitcnt vmcnt(0)" ::: "memory");
        __builtin_amdgcn_s_barrier();
#pragma unroll
        for (int kh = 0; kh < 2; kh++) {
            int kc = kh * 4 + (lane >> 4);
            short8 a[4], b[4];
#pragma unroll
            for (int mf = 0; mf < 4; mf++) {
                int r = wm * 64 + mf * 16 + (lane & 15);
                a[mf] = *(const short8*)(&As[cur][0] + kc * 1024 + r * 8);
            }
#pragma unroll
            for (int nf = 0; nf < 4; nf++) {
                int rb = wn * 64 + nf * 16 + (lane & 15);
                b[nf] = *(const short8*)(&Bs[cur][0] + kc * 1024 + rb * 8);
            }
            __builtin_amdgcn_s_setprio(1);
#pragma unroll
            for (int mf = 0; mf < 4; mf++)
#pragma unroll
                for (int nf = 0; nf < 4; nf++)
                    acc[mf][nf] = __builtin_amdgcn_mfma_f32_16x16x32_bf16(a[mf], b[nf], acc[mf][nf], 0, 0, 0);
            __builtin_amdgcn_s_setprio(0);
        }
        asm volatile("s_waitcnt lgkmcnt(0)" ::: "memory");
        __builtin_amdgcn_s_barrier();
        if (kt + 2 < 88) STAGE(cur, kt + 2);
        cur ^= 1;
    }

#pragma unroll
    for (int mf = 0; mf < 4; mf++)
#pragma unroll
        for (int nf = 0; nf < 4; nf++)
#pragma unroll
            for (int r = 0; r < 4; r++) {
                int row = wm * 64 + mf * 16 + ((lane >> 4) << 2) + r;
                int col = wn * 64 + nf * 16 + (lane & 15);
                if (m0 + row < c) {
                    float v = gws[row] * acc[mf][nf][r];
                    atomicAdd(&y[(size_t)toks[row] * DIM + n0 + col], v);
                }
            }
}

// =====================================================================
// FALLBACK (round-0 style): fp32 weights converted in-loop
// =====================================================================
__launch_bounds__(256)
__global__ void k_ffn1_fb(const unsigned short* __restrict__ xb,
                          const float* __restrict__ w1, const float* __restrict__ w3,
                          const int* __restrict__ cnt, const int* __restrict__ base,
                          const int* __restrict__ tok, unsigned short* __restrict__ hbuf) {
    int e  = blockIdx.x >> 4;
    int mt = blockIdx.x & 15;
    int c  = cnt[e];
    int m0 = mt * 128;
    if (m0 >= c) return;
    int gb = base[e];
    int n0 = blockIdx.y * 64;

    __shared__ unsigned short As[128 * 64];
    __shared__ unsigned short B1s[64 * 64];
    __shared__ unsigned short B3s[64 * 64];
    __shared__ int toks[128];

    int tid = threadIdx.x;
    if (tid < 128) {
        int s = m0 + tid;
        toks[tid] = (s < c) ? tok[gb + s] : tok[gb];
    }
    int lane = tid & 63, wid = tid >> 6;
    int wm = wid >> 1, wn = wid & 1;

    f32x4 acc1[4][2], acc3[4][2];
#pragma unroll
    for (int i = 0; i < 4; i++)
#pragma unroll
        for (int j = 0; j < 2; j++) { acc1[i][j] = (f32x4)0.f; acc3[i][j] = (f32x4)0.f; }

    const float* W1 = w1 + (size_t)e * NH * DIM + (size_t)n0 * DIM;
    const float* W3 = w3 + (size_t)e * NH * DIM + (size_t)n0 * DIM;

    for (int kt = 0; kt < DIM / 64; ++kt) {
        int k0 = kt * 64;
        __syncthreads();
#pragma unroll
        for (int i = 0; i < 4; i++) {
            int f = i * 256 + tid;
            int row = f >> 3, ch = f & 7;
            u32x4 v = *(const u32x4*)(xb + (size_t)toks[row] * DIM + k0 + ch * 8);
            *(u32x4*)(As + row * 64 + ((ch ^ (row & 7)) << 3)) = v;
        }
#pragma unroll
        for (int i = 0; i < 2; i++) {
            int f = i * 256 + tid;
            int row = f >> 3, ch = f & 7;
            {
                const float* src = W1 + (size_t)row * DIM + k0 + ch * 8;
                float4v a = *(const float4v*)src, b = *(const float4v*)(src + 4);
                short8 o;
                o[0]=(short)f2bf(a[0]); o[1]=(short)f2bf(a[1]); o[2]=(short)f2bf(a[2]); o[3]=(short)f2bf(a[3]);
                o[4]=(short)f2bf(b[0]); o[5]=(short)f2bf(b[1]); o[6]=(short)f2bf(b[2]); o[7]=(short)f2bf(b[3]);
                *(short8*)(B1s + row * 64 + ((ch ^ (row & 7)) << 3)) = o;
            }
            {
                const float* src = W3 + (size_t)row * DIM + k0 + ch * 8;
                float4v a = *(const float4v*)src, b = *(const float4v*)(src + 4);
                short8 o;
                o[0]=(short)f2bf(a[0]); o[1]=(short)f2bf(a[1]); o[2]=(short)f2bf(a[2]); o[3]=(short)f2bf(a[3]);
                o[4]=(short)f2bf(b[0]); o[5]=(short)f2bf(b[1]); o[6]=(short)f2bf(b[2]); o[7]=(short)f2bf(b[3]);
                *(short8*)(B3s + row * 64 + ((ch ^ (row & 7)) << 3)) = o;
            }
        }
        __syncthreads();
#pragma unroll
        for (int kk = 0; kk < 2; kk++) {
            int kch = kk * 4 + (lane >> 4);
            short8 af[4], b1f[2], b3f[2];
#pragma unroll
            for (int mf = 0; mf < 4; mf++) {
                int r = wm * 64 + mf * 16 + (lane & 15);
                af[mf] = *(const short8*)(As + r * 64 + ((kch ^ (r & 7)) << 3));
            }
#pragma unroll
            for (int nf = 0; nf < 2; nf++) {
                int r = wn * 32 + nf * 16 + (lane & 15);
                b1f[nf] = *(const short8*)(B1s + r * 64 + ((kch ^ (r & 7)) << 3));
                b3f[nf] = *(const short8*)(B3s + r * 64 + ((kch ^ (r & 7)) << 3));
            }
#pragma unroll
            for (int mf = 0; mf < 4; mf++)
#pragma unroll
                for (int nf = 0; nf < 2; nf++) {
                    acc1[mf][nf] = __builtin_amdgcn_mfma_f32_16x16x32_bf16(af[mf], b1f[nf], acc1[mf][nf], 0, 0, 0);
                    acc3[mf][nf] = __builtin_amdgcn_mfma_f32_16x16x32_bf16(af[mf], b3f[nf], acc3[mf][nf], 0, 0, 0);
                }
        }
    }
#pragma unroll
    for (int mf = 0; mf < 4; mf++)
#pragma unroll
        for (int nf = 0; nf < 2; nf++)
#pragma unroll
            for (int r = 0; r < 4; r++) {
                int row = wm * 64 + mf * 16 + ((lane >> 4) << 2) + r;
                int col = wn * 32 + nf * 16 + (lane & 15);
                if (m0 + row < c) {
                    float a = acc1[mf][nf][r];
                    float g = a / (1.f + expf(-a));
                    float v = g * acc3[mf][nf][r];
                    hbuf[(size_t)(gb + m0 + row) * NH + n0 + col] = f2bf(v);
                }
            }
}

__launch_bounds__(256)
__global__ void k_ffn2_fb(const unsigned short* __restrict__ hbuf,
                          const float* __restrict__ w2,
                          const int* __restrict__ cnt, const int* __restrict__ base,
                          const int* __restrict__ tok, const float* __restrict__ tw,
                          float* __restrict__ y) {
    int e  = blockIdx.x >> 4;
    int mt = blockIdx.x & 15;
    int c  = cnt[e];
    int m0 = mt * 128;
    if (m0 >= c) return;
    int gb = base[e];
    int n0 = blockIdx.y * 128;

    __shared__ unsigned short As[128 * 64];
    __shared__ unsigned short Bs[128 * 64];
    __shared__ int   toks[128];
    __shared__ float gws[128];

    int tid = threadIdx.x;
    if (tid < 128) {
        int s = m0 + tid;
        toks[tid] = (s < c) ? tok[gb + s] : 0;
        gws[tid]  = (s < c) ? tw[gb + s] : 0.f;
    }
    int lane = tid & 63, wid = tid >> 6;
    int wm = wid >> 1, wn = wid & 1;

    f32x4 acc[4][4];
#pragma unroll
    for (int i = 0; i < 4; i++)
#pragma unroll
        for (int j = 0; j < 4; j++) acc[i][j] = (f32x4)0.f;

    const float* W2 = w2 + (size_t)e * DIM * NH + (size_t)n0 * NH;

    for (int kt = 0; kt < NH / 64; ++kt) {
        int k0 = kt * 64;
        __syncthreads();
#pragma unroll
        for (int i = 0; i < 4; i++) {
            int f = i * 256 + tid;
            int row = f >> 3, ch = f & 7;
            int rr = m0 + row; rr = (rr < c) ? rr : (c - 1);
            u32x4 v = *(const u32x4*)(hbuf + (size_t)(gb + rr) * NH + k0 + ch * 8);
            *(u32x4*)(As + row * 64 + ((ch ^ (row & 7)) << 3)) = v;
        }
#pragma unroll
        for (int i = 0; i < 4; i++) {
            int f = i * 256 + tid;
            int row = f >> 3, ch = f & 7;
            const float* src = W2 + (size_t)row * NH + k0 + ch * 8;
            float4v a = *(const float4v*)src, b = *(const float4v*)(src + 4);
            short8 o;
            o[0]=(short)f2bf(a[0]); o[1]=(short)f2bf(a[1]); o[2]=(short)f2bf(a[2]); o[3]=(short)f2bf(a[3]);
            o[4]=(short)f2bf(b[0]); o[5]=(short)f2bf(b[1]); o[6]=(short)f2bf(b[2]); o[7]=(short)f2bf(b[3]);
            *(short8*)(Bs + row * 64 + ((ch ^ (row & 7)) << 3)) = o;
        }
        __syncthreads();
#pragma unroll
        for (int kk = 0; kk < 2; kk++) {
            int kch = kk * 4 + (lane >> 4);
            short8 af[4], bf[4];
#pragma unroll
            for (int mf = 0; mf < 4; mf++) {
                int r = wm * 64 + mf * 16 + (lane & 15);
                af[mf] = *(const short8*)(As + r * 64 + ((kch ^ (r & 7)) << 3));
            }
#pragma unroll
            for (int nf = 0; nf < 4; nf++) {
                int r = wn * 64 + nf * 16 + (lane & 15);
                bf[nf] = *(const short8*)(Bs + r * 64 + ((kch ^ (r & 7)) << 3));
            }
#pragma unroll
            for (int mf = 0; mf < 4; mf++)
#pragma unroll
                for (int nf = 0; nf < 4; nf++)
                    acc[mf][nf] = __builtin_amdgcn_mfma_f32_16x16x32_bf16(af[mf], bf[nf], acc[mf][nf], 0, 0, 0);
        }
    }
#pragma unroll
    for (int mf = 0; mf < 4; mf++)
#pragma unroll
        for (int nf = 0; nf < 4; nf++)
#pragma unroll
            for (int r = 0; r < 4; r++) {
                int row = wm * 64 + mf * 16 + ((lane >> 4) << 2) + r;
                int col = wn * 64 + nf * 16 + (lane & 15);
                if (m0 + row < c) {
                    float v = gws[row] * acc[mf][nf][r];
                    atomicAdd(&y[(size_t)toks[row] * DIM + n0 + col], v);
                }
            }
}

// ---------------- launch ----------------
extern "C" void kernel_launch(void* const* d_in, const int* in_sizes, int n_in,
                              void* d_out, int out_size, void* d_ws, size_t ws_size,
                              hipStream_t stream) {
    const float* x  = (const float*)d_in[0];
    const float* gw = (const float*)d_in[1];
    const float* w1 = (const float*)d_in[2];
    const float* w2 = (const float*)d_in[3];
    const float* w3 = (const float*)d_in[4];
    float* y = (float*)d_out;

    char* ws = (char*)d_ws;
    int*   cnt  = (int*)(ws + 0);
    int*   run  = (int*)(ws + 64);
    int*   basep= (int*)(ws + 128);
    int*   pb   = (int*)(ws + 192);
    int*   tok  = (int*)(ws + 256);
    float* tw   = (float*)(ws + 16640);
    int*   rt_e = (int*)(ws + 33024);
    float* rt_w = (float*)(ws + 49408);
    unsigned short* xp    = (unsigned short*)(ws + 66048);       // 20,971,520 B (also xb in fallback)
    unsigned short* hbufp = (unsigned short*)(ws + 21037568);    // 57,671,680 B (also hbuf flat in fallback)
    unsigned short* w1p   = (unsigned short*)(ws + 78709248);    // 184,549,376 B
    unsigned short* w3p   = (unsigned short*)(ws + 263258624);   // 184,549,376 B
    unsigned short* w2p   = (unsigned short*)(ws + 447808000);   // 184,549,376 B
    const size_t needed = 632357376ull;

    hipMemsetAsync(ws, 0, 256, stream);
    hipMemsetAsync(d_out, 0, (size_t)out_size * sizeof(float), stream);

    k_gate<<<T_TOK / 4, 256, 0, stream>>>(x, gw, rt_e, rt_w, cnt);
    k_base<<<1, 64, 0, stream>>>(cnt, basep, pb);
    k_assign<<<T_TOK / 256, 256, 0, stream>>>(rt_e, rt_w, basep, run, tok, tw);

    if (ws_size >= needed) {
        k_packw13<<<dim3(32, 88, 16), 256, 0, stream>>>(w1, w3, w1p, w3p);
        k_packw2<<<dim3(88, 16, NE), 256, 0, stream>>>(w2, w2p);
        k_xpack<<<dim3(32, 16, NE), 256, 0, stream>>>(x, cnt, basep, pb, tok, xp);
        int nwg1 = NE * 16 * 88;     // 11264
        int nwg2 = NE * 16 * 16;     // 2048
        k_ffn1<<<nwg1, 256, 0, stream>>>(xp, w1p, w3p, cnt, pb, hbufp, nwg1);
        k_ffn2<<<nwg2, 256, 0, stream>>>(hbufp, w2p, cnt, basep, pb, tok, tw, y, nwg2);
    } else {
        k_cvt<<<(T_TOK * DIM / 8) / 256, 256, 0, stream>>>(x, xp, T_TOK * DIM / 8);
        k_ffn1_fb<<<dim3(NE * 16, NH / 64), 256, 0, stream>>>(xp, w1, w3, cnt, basep, tok, hbufp);
        k_ffn2_fb<<<dim3(NE * 16, DIM / 128), 256, 0, stream>>>(hbufp, w2, cnt, basep, tok, tw, y);
    }
}

// Round 5
// 884.808 us; speedup vs baseline: 2.4271x; 1.3069x over previous
//
#include <hip/hip_runtime.h>
#include <hip/hip_bf16.h>

#define T_TOK 2048
#define DIM   2048
#define NE    8
#define NH    5632

typedef __attribute__((ext_vector_type(4))) float f32x4;
typedef __attribute__((ext_vector_type(8))) short short8;
typedef __attribute__((ext_vector_type(4))) unsigned int u32x4;
typedef __attribute__((ext_vector_type(4))) float float4v;

__device__ inline unsigned short f2bf(float f) {
    unsigned u = __builtin_bit_cast(unsigned, f);
    u += 0x7fffu + ((u >> 16) & 1u);       // round-to-nearest-even
    return (unsigned short)(u >> 16);
}

__device__ __forceinline__ void glds16(const void* g, void* l) {
    __builtin_amdgcn_global_load_lds((const __attribute__((address_space(1))) void*)g,
                                     (__attribute__((address_space(3))) void*)l, 16, 0, 0);
}

// ---------------- fp32 -> bf16 flat convert (fallback path only) ----------------
__global__ void k_cvt(const float* __restrict__ src, unsigned short* __restrict__ dst, int n8) {
    int i = blockIdx.x * blockDim.x + threadIdx.x;
    if (i >= n8) return;
    const float4v* xv = (const float4v*)src;
    float4v a = xv[2 * i], b = xv[2 * i + 1];
    short8 o;
    o[0] = (short)f2bf(a[0]); o[1] = (short)f2bf(a[1]);
    o[2] = (short)f2bf(a[2]); o[3] = (short)f2bf(a[3]);
    o[4] = (short)f2bf(b[0]); o[5] = (short)f2bf(b[1]);
    o[6] = (short)f2bf(b[2]); o[7] = (short)f2bf(b[3]);
    ((short8*)dst)[i] = o;
}

// ---------------- gating + count fused (fp32, one wave per token) ----------------
__global__ void k_gate(const float* __restrict__ x, const float* __restrict__ gw,
                       int* __restrict__ rt_e, float* __restrict__ rt_w, int* __restrict__ cnt) {
    int wid = threadIdx.x >> 6, lane = threadIdx.x & 63;
    int t = blockIdx.x * 4 + wid;
    if (t >= T_TOK) return;
    float acc[NE];
#pragma unroll
    for (int e = 0; e < NE; e++) acc[e] = 0.f;
    const float* xr = x + (size_t)t * DIM;
    for (int d = lane; d < DIM; d += 64) {
        float xv = xr[d];
#pragma unroll
        for (int e = 0; e < NE; e++) acc[e] += xv * gw[e * DIM + d];
    }
#pragma unroll
    for (int e = 0; e < NE; e++) {
        float v = acc[e];
#pragma unroll
        for (int off = 32; off; off >>= 1) v += __shfl_xor(v, off);
        acc[e] = v;
    }
    if (lane == 0) {
        int i0 = 0; float s0 = acc[0];
#pragma unroll
        for (int e = 1; e < NE; e++) if (acc[e] > s0) { s0 = acc[e]; i0 = e; }
        int i1 = -1; float s1 = -1e30f;
#pragma unroll
        for (int e = 0; e < NE; e++) if (e != i0 && acc[e] > s1) { s1 = acc[e]; i1 = e; }
        float w0 = 1.f / (1.f + expf(s1 - s0));
        rt_e[2 * t] = i0; rt_e[2 * t + 1] = i1;
        rt_w[2 * t] = w0; rt_w[2 * t + 1] = 1.f - w0;
        atomicAdd(&cnt[i0], 1);
        atomicAdd(&cnt[i1], 1);
    }
}

// exclusive prefix (slot base) + padded-tile prefix (128-row tiles)
__global__ void k_base(const int* __restrict__ cnt, int* __restrict__ base, int* __restrict__ pb) {
    if (threadIdx.x == 0) {
        int s = 0, p = 0;
        for (int e = 0; e < NE; e++) {
            base[e] = s; pb[e] = p;
            s += cnt[e];
            p += ((cnt[e] + 127) >> 7) << 7;
        }
    }
}

__global__ void k_assign(const int* __restrict__ rt_e, const float* __restrict__ rt_w,
                         const int* __restrict__ base, int* __restrict__ run,
                         int* __restrict__ tok, float* __restrict__ tw) {
    int t = blockIdx.x * blockDim.x + threadIdx.x;
    if (t >= T_TOK) return;
#pragma unroll
    for (int k = 0; k < 2; k++) {
        int e = rt_e[2 * t + k];
        int p = atomicAdd(&run[e], 1);
        int g = base[e] + p;
        tok[g] = t;
        tw[g] = rt_w[2 * t + k];
    }
}

// ---------------- weight convert+pack w1 & w3: fp32 [E][NH][DIM] -> [e][nt88][kt32][kc8][row64][8] ----------------
__global__ void k_packw13(const float* __restrict__ w1, const float* __restrict__ w3,
                          unsigned short* __restrict__ w1p, unsigned short* __restrict__ w3p) {
    int z = blockIdx.z;                       // 0..15
    const float* src = (z < 8) ? w1 : w3;
    unsigned short* dst = (z < 8) ? w1p : w3p;
    int e = z & 7, nt = blockIdx.y, kt = blockIdx.x;
    int lane = threadIdx.x & 63, w = threadIdx.x >> 6;
    int kc = lane & 7;
    const float* sb = src + (size_t)e * NH * DIM;
    unsigned short* db = dst + ((size_t)(e * 88 + nt) * 32 + kt) * 4096;
#pragma unroll
    for (int it = 0; it < 2; ++it) {
        int rloc = it * 32 + w * 8 + (lane >> 3);
        const float* s = sb + (size_t)(nt * 64 + rloc) * DIM + kt * 64 + kc * 8;
        float4v a = *(const float4v*)s, b = *(const float4v*)(s + 4);
        short8 o;
        o[0]=(short)f2bf(a[0]); o[1]=(short)f2bf(a[1]); o[2]=(short)f2bf(a[2]); o[3]=(short)f2bf(a[3]);
        o[4]=(short)f2bf(b[0]); o[5]=(short)f2bf(b[1]); o[6]=(short)f2bf(b[2]); o[7]=(short)f2bf(b[3]);
        *(short8*)(db + kc * 512 + rloc * 8) = o;
    }
}

// ---------------- weight convert+pack w2: fp32 [E][DIM][NH] -> [e][nt16][kt88][kc8][row128][8] ----------------
__global__ void k_packw2(const float* __restrict__ w2, unsigned short* __restrict__ w2p) {
    int e = blockIdx.z, nt = blockIdx.y, kt = blockIdx.x;   // (88, 16, 8)
    int lane = threadIdx.x & 63, w = threadIdx.x >> 6;
    int kc = lane & 7;
    const float* sb = w2 + (size_t)e * DIM * NH;
    unsigned short* db = w2p + ((size_t)(e * 16 + nt) * 88 + kt) * 8192;
#pragma unroll
    for (int it = 0; it < 4; ++it) {
        int rloc = it * 32 + w * 8 + (lane >> 3);
        const float* s = sb + (size_t)(nt * 128 + rloc) * NH + kt * 64 + kc * 8;
        float4v a = *(const float4v*)s, b = *(const float4v*)(s + 4);
        short8 o;
        o[0]=(short)f2bf(a[0]); o[1]=(short)f2bf(a[1]); o[2]=(short)f2bf(a[2]); o[3]=(short)f2bf(a[3]);
        o[4]=(short)f2bf(b[0]); o[5]=(short)f2bf(b[1]); o[6]=(short)f2bf(b[2]); o[7]=(short)f2bf(b[3]);
        *(short8*)(db + kc * 1024 + rloc * 8) = o;
    }
}

// ---------------- x gather+convert+pack: [ptile][kt32][kc8][row128][8] ----------------
__global__ void k_xpack(const float* __restrict__ x,
                        const int* __restrict__ cnt, const int* __restrict__ base,
                        const int* __restrict__ pb, const int* __restrict__ tok,
                        unsigned short* __restrict__ xp) {
    int e = blockIdx.z, mt = blockIdx.y, kt = blockIdx.x;
    int c = cnt[e], m0 = mt * 128;
    if (m0 >= c) return;
    int gb = base[e];
    int ptile = (pb[e] >> 7) + mt;
    int lane = threadIdx.x & 63, w = threadIdx.x >> 6;
    int kc = lane & 7;
    unsigned short* db = xp + (size_t)ptile * 262144 + (size_t)kt * 8192;
#pragma unroll
    for (int it = 0; it < 4; ++it) {
        int rloc = it * 32 + w * 8 + (lane >> 3);
        int slot = m0 + rloc;
        int t = tok[gb + (slot < c ? slot : 0)];
        const float* s = x + (size_t)t * DIM + kt * 64 + kc * 8;
        float4v a = *(const float4v*)s, b = *(const float4v*)(s + 4);
        short8 o;
        o[0]=(short)f2bf(a[0]); o[1]=(short)f2bf(a[1]); o[2]=(short)f2bf(a[2]); o[3]=(short)f2bf(a[3]);
        o[4]=(short)f2bf(b[0]); o[5]=(short)f2bf(b[1]); o[6]=(short)f2bf(b[2]); o[7]=(short)f2bf(b[3]);
        *(short8*)(db + kc * 1024 + rloc * 8) = o;
    }
}

// =====================================================================
// GEMM1: h = silu(x@w1^T)*(x@w3^T). 128Mx64N dual, BK=64, 4 waves.
// m97 structure: single 32KB LDS buffer, 2-barrier loop, 4 blocks/CU.
// =====================================================================
__launch_bounds__(256, 4)
__global__ void k_ffn1(const unsigned short* __restrict__ xp,
                       const unsigned short* __restrict__ w1p, const unsigned short* __restrict__ w3p,
                       const int* __restrict__ cnt, const int* __restrict__ pb,
                       unsigned short* __restrict__ hb, int nwg) {
    int bid = blockIdx.x;
    int swz = (bid & 7) * (nwg >> 3) + (bid >> 3);
    int mt = swz & 15;
    int r2 = swz >> 4;
    int nt = r2 % 88;
    int e  = r2 / 88;
    int c  = cnt[e];
    int m0 = mt * 128;
    if (m0 >= c) return;
    int ptile = (pb[e] >> 7) + mt;

    __shared__ unsigned short As[8192];   // 16KB: [kc8][row128][8]
    __shared__ unsigned short B1[4096];   // 8KB:  [kc8][row64][8]
    __shared__ unsigned short B3[4096];

    int tid = threadIdx.x;
    int lane = tid & 63, w = tid >> 6;
    int wm = w >> 1, wn = w & 1;
    int half = w & 1, wh = w >> 1;

    const unsigned short* aB  = xp  + (size_t)ptile * 262144 + half * 512 + lane * 8;
    const unsigned short* b1B = w1p + (size_t)(e * 88 + nt) * 131072 + lane * 8;
    const unsigned short* b3B = w3p + (size_t)(e * 88 + nt) * 131072 + lane * 8;

    f32x4 acc1[4][2], acc3[4][2];
#pragma unroll
    for (int i = 0; i < 4; i++)
#pragma unroll
        for (int j = 0; j < 2; j++) { acc1[i][j] = (f32x4)0.f; acc3[i][j] = (f32x4)0.f; }

    for (int kt = 0; kt < 32; ++kt) {
        __syncthreads();                  // prior compute done with LDS
        // stage: 8 glds16 per thread, each 1KB-contiguous per wave
#pragma unroll
        for (int i = 0; i < 4; i++) {
            int kc = i * 2 + wh;
            glds16(aB + kt * 8192 + kc * 1024, (char*)As + kc * 2048 + half * 1024);
        }
#pragma unroll
        for (int i = 0; i < 2; i++) {
            int kc = i * 4 + w;
            glds16(b1B + kt * 4096 + kc * 512, (char*)B1 + kc * 1024);
            glds16(b3B + kt * 4096 + kc * 512, (char*)B3 + kc * 1024);
        }
        asm volatile("s_waitcnt vmcnt(0)" ::: "memory");
        __syncthreads();
#pragma unroll
        for (int kh = 0; kh < 2; kh++) {
            int kc = kh * 4 + (lane >> 4);
            short8 a[4], b1[2], b3[2];
#pragma unroll
            for (int mf = 0; mf < 4; mf++) {
                int r = wm * 64 + mf * 16 + (lane & 15);
                a[mf] = *(const short8*)(As + kc * 1024 + r * 8);
            }
#pragma unroll
            for (int nf = 0; nf < 2; nf++) {
                int rb = wn * 32 + nf * 16 + (lane & 15);
                b1[nf] = *(const short8*)(B1 + kc * 512 + rb * 8);
                b3[nf] = *(const short8*)(B3 + kc * 512 + rb * 8);
            }
#pragma unroll
            for (int mf = 0; mf < 4; mf++)
#pragma unroll
                for (int nf = 0; nf < 2; nf++) {
                    acc1[mf][nf] = __builtin_amdgcn_mfma_f32_16x16x32_bf16(a[mf], b1[nf], acc1[mf][nf], 0, 0, 0);
                    acc3[mf][nf] = __builtin_amdgcn_mfma_f32_16x16x32_bf16(a[mf], b3[nf], acc3[mf][nf], 0, 0, 0);
                }
        }
    }

    // epilogue: h -> packed hbufp [ptile][kt_h=nt][kc][row][8]
    unsigned short* hT = hb + ((size_t)ptile * 88 + nt) * 8192;
#pragma unroll
    for (int mf = 0; mf < 4; mf++)
#pragma unroll
        for (int nf = 0; nf < 2; nf++)
#pragma unroll
            for (int r = 0; r < 4; r++) {
                int row = wm * 64 + mf * 16 + ((lane >> 4) << 2) + r;
                int col = wn * 32 + nf * 16 + (lane & 15);
                if (m0 + row < c) {
                    float a = acc1[mf][nf][r];
                    float g = a / (1.f + expf(-a));
                    float v = g * acc3[mf][nf][r];
                    hT[(col >> 3) * 1024 + row * 8 + (col & 7)] = f2bf(v);
                }
            }
}

// =====================================================================
// GEMM2: y[t] += gate_w * (h @ w2^T). 128Mx128N, BK=64, 4 waves.
// m97 structure: single 32KB LDS buffer, 2-barrier loop, 4 blocks/CU.
// =====================================================================
__launch_bounds__(256, 4)
__global__ void k_ffn2(const unsigned short* __restrict__ hb,
                       const unsigned short* __restrict__ w2p,
                       const int* __restrict__ cnt, const int* __restrict__ base,
                       const int* __restrict__ pb,
                       const int* __restrict__ tok, const float* __restrict__ tw,
                       float* __restrict__ y, int nwg) {
    int bid = blockIdx.x;
    int swz = (bid & 7) * (nwg >> 3) + (bid >> 3);
    int mt = swz & 15;
    int r2 = swz >> 4;
    int nt = r2 & 15;
    int e  = r2 >> 4;
    int c  = cnt[e];
    int m0 = mt * 128;
    if (m0 >= c) return;
    int gb = base[e];
    int ptile = (pb[e] >> 7) + mt;
    int n0 = nt * 128;

    __shared__ unsigned short As[8192];
    __shared__ unsigned short Bs[8192];
    __shared__ int   toks[128];
    __shared__ float gws[128];

    int tid = threadIdx.x;
    if (tid < 128) {
        int s = m0 + tid;
        toks[tid] = (s < c) ? tok[gb + s] : 0;
        gws[tid]  = (s < c) ? tw[gb + s] : 0.f;
    }

    int lane = tid & 63, w = tid >> 6;
    int wm = w >> 1, wn = w & 1;
    int half = w & 1, wh = w >> 1;

    const unsigned short* aB = hb  + (size_t)ptile * 720896 + half * 512 + lane * 8;
    const unsigned short* bB = w2p + (size_t)(e * 16 + nt) * 720896 + half * 512 + lane * 8;

    f32x4 acc[4][4];
#pragma unroll
    for (int i = 0; i < 4; i++)
#pragma unroll
        for (int j = 0; j < 4; j++) acc[i][j] = (f32x4)0.f;

    for (int kt = 0; kt < 88; ++kt) {
        __syncthreads();
#pragma unroll
        for (int i = 0; i < 4; i++) {
            int kc = i * 2 + wh;
            glds16(aB + kt * 8192 + kc * 1024, (char*)As + kc * 2048 + half * 1024);
            glds16(bB + kt * 8192 + kc * 1024, (char*)Bs + kc * 2048 + half * 1024);
        }
        asm volatile("s_waitcnt vmcnt(0)" ::: "memory");
        __syncthreads();
#pragma unroll
        for (int kh = 0; kh < 2; kh++) {
            int kc = kh * 4 + (lane >> 4);
            short8 a[4], b[4];
#pragma unroll
            for (int mf = 0; mf < 4; mf++) {
                int r = wm * 64 + mf * 16 + (lane & 15);
                a[mf] = *(const short8*)(As + kc * 1024 + r * 8);
            }
#pragma unroll
            for (int nf = 0; nf < 4; nf++) {
                int rb = wn * 64 + nf * 16 + (lane & 15);
                b[nf] = *(const short8*)(Bs + kc * 1024 + rb * 8);
            }
#pragma unroll
            for (int mf = 0; mf < 4; mf++)
#pragma unroll
                for (int nf = 0; nf < 4; nf++)
                    acc[mf][nf] = __builtin_amdgcn_mfma_f32_16x16x32_bf16(a[mf], b[nf], acc[mf][nf], 0, 0, 0);
        }
    }

#pragma unroll
    for (int mf = 0; mf < 4; mf++)
#pragma unroll
        for (int nf = 0; nf < 4; nf++)
#pragma unroll
            for (int r = 0; r < 4; r++) {
                int row = wm * 64 + mf * 16 + ((lane >> 4) << 2) + r;
                int col = wn * 64 + nf * 16 + (lane & 15);
                if (m0 + row < c) {
                    float v = gws[row] * acc[mf][nf][r];
                    atomicAdd(&y[(size_t)toks[row] * DIM + n0 + col], v);
                }
            }
}

// =====================================================================
// FALLBACK (round-0 style): fp32 weights converted in-loop
// =====================================================================
__launch_bounds__(256)
__global__ void k_ffn1_fb(const unsigned short* __restrict__ xb,
                          const float* __restrict__ w1, const float* __restrict__ w3,
                          const int* __restrict__ cnt, const int* __restrict__ base,
                          const int* __restrict__ tok, unsigned short* __restrict__ hbuf) {
    int e  = blockIdx.x >> 4;
    int mt = blockIdx.x & 15;
    int c  = cnt[e];
    int m0 = mt * 128;
    if (m0 >= c) return;
    int gb = base[e];
    int n0 = blockIdx.y * 64;

    __shared__ unsigned short As[128 * 64];
    __shared__ unsigned short B1s[64 * 64];
    __shared__ unsigned short B3s[64 * 64];
    __shared__ int toks[128];

    int tid = threadIdx.x;
    if (tid < 128) {
        int s = m0 + tid;
        toks[tid] = (s < c) ? tok[gb + s] : tok[gb];
    }
    int lane = tid & 63, wid = tid >> 6;
    int wm = wid >> 1, wn = wid & 1;

    f32x4 acc1[4][2], acc3[4][2];
#pragma unroll
    for (int i = 0; i < 4; i++)
#pragma unroll
        for (int j = 0; j < 2; j++) { acc1[i][j] = (f32x4)0.f; acc3[i][j] = (f32x4)0.f; }

    const float* W1 = w1 + (size_t)e * NH * DIM + (size_t)n0 * DIM;
    const float* W3 = w3 + (size_t)e * NH * DIM + (size_t)n0 * DIM;

    for (int kt = 0; kt < DIM / 64; ++kt) {
        int k0 = kt * 64;
        __syncthreads();
#pragma unroll
        for (int i = 0; i < 4; i++) {
            int f = i * 256 + tid;
            int row = f >> 3, ch = f & 7;
            u32x4 v = *(const u32x4*)(xb + (size_t)toks[row] * DIM + k0 + ch * 8);
            *(u32x4*)(As + row * 64 + ((ch ^ (row & 7)) << 3)) = v;
        }
#pragma unroll
        for (int i = 0; i < 2; i++) {
            int f = i * 256 + tid;
            int row = f >> 3, ch = f & 7;
            {
                const float* src = W1 + (size_t)row * DIM + k0 + ch * 8;
                float4v a = *(const float4v*)src, b = *(const float4v*)(src + 4);
                short8 o;
                o[0]=(short)f2bf(a[0]); o[1]=(short)f2bf(a[1]); o[2]=(short)f2bf(a[2]); o[3]=(short)f2bf(a[3]);
                o[4]=(short)f2bf(b[0]); o[5]=(short)f2bf(b[1]); o[6]=(short)f2bf(b[2]); o[7]=(short)f2bf(b[3]);
                *(short8*)(B1s + row * 64 + ((ch ^ (row & 7)) << 3)) = o;
            }
            {
                const float* src = W3 + (size_t)row * DIM + k0 + ch * 8;
                float4v a = *(const float4v*)src, b = *(const float4v*)(src + 4);
                short8 o;
                o[0]=(short)f2bf(a[0]); o[1]=(short)f2bf(a[1]); o[2]=(short)f2bf(a[2]); o[3]=(short)f2bf(a[3]);
                o[4]=(short)f2bf(b[0]); o[5]=(short)f2bf(b[1]); o[6]=(short)f2bf(b[2]); o[7]=(short)f2bf(b[3]);
                *(short8*)(B3s + row * 64 + ((ch ^ (row & 7)) << 3)) = o;
            }
        }
        __syncthreads();
#pragma unroll
        for (int kk = 0; kk < 2; kk++) {
            int kch = kk * 4 + (lane >> 4);
            short8 af[4], b1f[2], b3f[2];
#pragma unroll
            for (int mf = 0; mf < 4; mf++) {
                int r = wm * 64 + mf * 16 + (lane & 15);
                af[mf] = *(const short8*)(As + r * 64 + ((kch ^ (r & 7)) << 3));
            }
#pragma unroll
            for (int nf = 0; nf < 2; nf++) {
                int r = wn * 32 + nf * 16 + (lane & 15);
                b1f[nf] = *(const short8*)(B1s + r * 64 + ((kch ^ (r & 7)) << 3));
                b3f[nf] = *(const short8*)(B3s + r * 64 + ((kch ^ (r & 7)) << 3));
            }
#pragma unroll
            for (int mf = 0; mf < 4; mf++)
#pragma unroll
                for (int nf = 0; nf < 2; nf++) {
                    acc1[mf][nf] = __builtin_amdgcn_mfma_f32_16x16x32_bf16(af[mf], b1f[nf], acc1[mf][nf], 0, 0, 0);
                    acc3[mf][nf] = __builtin_amdgcn_mfma_f32_16x16x32_bf16(af[mf], b3f[nf], acc3[mf][nf], 0, 0, 0);
                }
        }
    }
#pragma unroll
    for (int mf = 0; mf < 4; mf++)
#pragma unroll
        for (int nf = 0; nf < 2; nf++)
#pragma unroll
            for (int r = 0; r < 4; r++) {
                int row = wm * 64 + mf * 16 + ((lane >> 4) << 2) + r;
                int col = wn * 32 + nf * 16 + (lane & 15);
                if (m0 + row < c) {
                    float a = acc1[mf][nf][r];
                    float g = a / (1.f + expf(-a));
                    float v = g * acc3[mf][nf][r];
                    hbuf[(size_t)(gb + m0 + row) * NH + n0 + col] = f2bf(v);
                }
            }
}

__launch_bounds__(256)
__global__ void k_ffn2_fb(const unsigned short* __restrict__ hbuf,
                          const float* __restrict__ w2,
                          const int* __restrict__ cnt, const int* __restrict__ base,
                          const int* __restrict__ tok, const float* __restrict__ tw,
                          float* __restrict__ y) {
    int e  = blockIdx.x >> 4;
    int mt = blockIdx.x & 15;
    int c  = cnt[e];
    int m0 = mt * 128;
    if (m0 >= c) return;
    int gb = base[e];
    int n0 = blockIdx.y * 128;

    __shared__ unsigned short As[128 * 64];
    __shared__ unsigned short Bs[128 * 64];
    __shared__ int   toks[128];
    __shared__ float gws[128];

    int tid = threadIdx.x;
    if (tid < 128) {
        int s = m0 + tid;
        toks[tid] = (s < c) ? tok[gb + s] : 0;
        gws[tid]  = (s < c) ? tw[gb + s] : 0.f;
    }
    int lane = tid & 63, wid = tid >> 6;
    int wm = wid >> 1, wn = wid & 1;

    f32x4 acc[4][4];
#pragma unroll
    for (int i = 0; i < 4; i++)
#pragma unroll
        for (int j = 0; j < 4; j++) acc[i][j] = (f32x4)0.f;

    const float* W2 = w2 + (size_t)e * DIM * NH + (size_t)n0 * NH;

    for (int kt = 0; kt < NH / 64; ++kt) {
        int k0 = kt * 64;
        __syncthreads();
#pragma unroll
        for (int i = 0; i < 4; i++) {
            int f = i * 256 + tid;
            int row = f >> 3, ch = f & 7;
            int rr = m0 + row; rr = (rr < c) ? rr : (c - 1);
            u32x4 v = *(const u32x4*)(hbuf + (size_t)(gb + rr) * NH + k0 + ch * 8);
            *(u32x4*)(As + row * 64 + ((ch ^ (row & 7)) << 3)) = v;
        }
#pragma unroll
        for (int i = 0; i < 4; i++) {
            int f = i * 256 + tid;
            int row = f >> 3, ch = f & 7;
            const float* src = W2 + (size_t)row * NH + k0 + ch * 8;
            float4v a = *(const float4v*)src, b = *(const float4v*)(src + 4);
            short8 o;
            o[0]=(short)f2bf(a[0]); o[1]=(short)f2bf(a[1]); o[2]=(short)f2bf(a[2]); o[3]=(short)f2bf(a[3]);
            o[4]=(short)f2bf(b[0]); o[5]=(short)f2bf(b[1]); o[6]=(short)f2bf(b[2]); o[7]=(short)f2bf(b[3]);
            *(short8*)(Bs + row * 64 + ((ch ^ (row & 7)) << 3)) = o;
        }
        __syncthreads();
#pragma unroll
        for (int kk = 0; kk < 2; kk++) {
            int kch = kk * 4 + (lane >> 4);
            short8 af[4], bf[4];
#pragma unroll
            for (int mf = 0; mf < 4; mf++) {
                int r = wm * 64 + mf * 16 + (lane & 15);
                af[mf] = *(const short8*)(As + r * 64 + ((kch ^ (r & 7)) << 3));
            }
#pragma unroll
            for (int nf = 0; nf < 4; nf++) {
                int r = wn * 64 + nf * 16 + (lane & 15);
                bf[nf] = *(const short8*)(Bs + r * 64 + ((kch ^ (r & 7)) << 3));
            }
#pragma unroll
            for (int mf = 0; mf < 4; mf++)
#pragma unroll
                for (int nf = 0; nf < 4; nf++)
                    acc[mf][nf] = __builtin_amdgcn_mfma_f32_16x16x32_bf16(af[mf], bf[nf], acc[mf][nf], 0, 0, 0);
        }
    }
#pragma unroll
    for (int mf = 0; mf < 4; mf++)
#pragma unroll
        for (int nf = 0; nf < 4; nf++)
#pragma unroll
            for (int r = 0; r < 4; r++) {
                int row = wm * 64 + mf * 16 + ((lane >> 4) << 2) + r;
                int col = wn * 64 + nf * 16 + (lane & 15);
                if (m0 + row < c) {
                    float v = gws[row] * acc[mf][nf][r];
                    atomicAdd(&y[(size_t)toks[row] * DIM + n0 + col], v);
                }
            }
}

// ---------------- launch ----------------
extern "C" void kernel_launch(void* const* d_in, const int* in_sizes, int n_in,
                              void* d_out, int out_size, void* d_ws, size_t ws_size,
                              hipStream_t stream) {
    const float* x  = (const float*)d_in[0];
    const float* gw = (const float*)d_in[1];
    const float* w1 = (const float*)d_in[2];
    const float* w2 = (const float*)d_in[3];
    const float* w3 = (const float*)d_in[4];
    float* y = (float*)d_out;

    char* ws = (char*)d_ws;
    int*   cnt  = (int*)(ws + 0);
    int*   run  = (int*)(ws + 64);
    int*   basep= (int*)(ws + 128);
    int*   pb   = (int*)(ws + 192);
    int*   tok  = (int*)(ws + 256);
    float* tw   = (float*)(ws + 16640);
    int*   rt_e = (int*)(ws + 33024);
    float* rt_w = (float*)(ws + 49408);
    unsigned short* xp    = (unsigned short*)(ws + 66048);       // 20,971,520 B (also xb in fallback)
    unsigned short* hbufp = (unsigned short*)(ws + 21037568);    // 57,671,680 B (also hbuf flat in fallback)
    unsigned short* w1p   = (unsigned short*)(ws + 78709248);    // 184,549,376 B
    unsigned short* w3p   = (unsigned short*)(ws + 263258624);   // 184,549,376 B
    unsigned short* w2p   = (unsigned short*)(ws + 447808000);   // 184,549,376 B
    const size_t needed = 632357376ull;

    hipMemsetAsync(ws, 0, 256, stream);
    hipMemsetAsync(d_out, 0, (size_t)out_size * sizeof(float), stream);

    k_gate<<<T_TOK / 4, 256, 0, stream>>>(x, gw, rt_e, rt_w, cnt);
    k_base<<<1, 64, 0, stream>>>(cnt, basep, pb);
    k_assign<<<T_TOK / 256, 256, 0, stream>>>(rt_e, rt_w, basep, run, tok, tw);

    if (ws_size >= needed) {
        k_packw13<<<dim3(32, 88, 16), 256, 0, stream>>>(w1, w3, w1p, w3p);
        k_packw2<<<dim3(88, 16, NE), 256, 0, stream>>>(w2, w2p);
        k_xpack<<<dim3(32, 16, NE), 256, 0, stream>>>(x, cnt, basep, pb, tok, xp);
        int nwg1 = NE * 16 * 88;     // 11264
        int nwg2 = NE * 16 * 16;     // 2048
        k_ffn1<<<nwg1, 256, 0, stream>>>(xp, w1p, w3p, cnt, pb, hbufp, nwg1);
        k_ffn2<<<nwg2, 256, 0, stream>>>(hbufp, w2p, cnt, basep, pb, tok, tw, y, nwg2);
    } else {
        k_cvt<<<(T_TOK * DIM / 8) / 256, 256, 0, stream>>>(x, xp, T_TOK * DIM / 8);
        k_ffn1_fb<<<dim3(NE * 16, NH / 64), 256, 0, stream>>>(xp, w1, w3, cnt, basep, tok, hbufp);
        k_ffn2_fb<<<dim3(NE * 16, DIM / 128), 256, 0, stream>>>(hbufp, w2, cnt, basep, tok, tw, y);
    }
}